// Round 3
// baseline (918.462 us; speedup 1.0000x reference)
//
#include <hip/hip_runtime.h>
#include <hip/hip_fp16.h>

namespace {

constexpr int BATCH = 16;
constexpr int NSP   = 4096;   // 64*64
constexpr int CQKV  = 768;
constexpr float EPS = 1e-15f;

struct alignas(8) Half4 { __half v[4]; };

// ---------------- qkv conv1x1 as GEMM: Out[b,o,n] = sum_c W[o,c] * X[b,c,n] ----------------
// tile: 128 o x 64 n, BK=16, 256 threads, each thread 8x4 outputs; fp32 in, fp16 out
__global__ __launch_bounds__(256)
void qkv_gemm_kernel(const float* __restrict__ X, const float* __restrict__ Wt,
                     __half* __restrict__ Out) {
  const int b     = blockIdx.z;
  const int oBase = blockIdx.y * 128;
  const int nBase = blockIdx.x * 64;
  __shared__ float Ws[16][132];   // [k][o], padded
  __shared__ float Xs[16][68];    // [k][n], padded
  const int tid = threadIdx.x;
  const int tx  = tid & 15;   // n quad
  const int ty  = tid >> 4;   // o octet
  float acc[8][4];
#pragma unroll
  for (int i = 0; i < 8; ++i)
#pragma unroll
    for (int j = 0; j < 4; ++j) acc[i][j] = 0.f;

  const float* Xb = X + (size_t)b * 256 * NSP;

  for (int k0 = 0; k0 < 256; k0 += 16) {
    {
      const int o  = tid >> 1;
      const int kk = (tid & 1) * 8;
      const float* wp = Wt + (size_t)(oBase + o) * 256 + k0 + kk;
      float4 w0 = *(const float4*)wp;
      float4 w1 = *(const float4*)(wp + 4);
      Ws[kk + 0][o] = w0.x; Ws[kk + 1][o] = w0.y;
      Ws[kk + 2][o] = w0.z; Ws[kk + 3][o] = w0.w;
      Ws[kk + 4][o] = w1.x; Ws[kk + 5][o] = w1.y;
      Ws[kk + 6][o] = w1.z; Ws[kk + 7][o] = w1.w;
    }
    {
      const int k  = tid >> 4;
      const int nn = (tid & 15) * 4;
      *(float4*)&Xs[k][nn] = *(const float4*)&Xb[(size_t)(k0 + k) * NSP + nBase + nn];
    }
    __syncthreads();
#pragma unroll
    for (int k = 0; k < 16; ++k) {
      float4 a0 = *(const float4*)&Ws[k][ty * 8];
      float4 a1 = *(const float4*)&Ws[k][ty * 8 + 4];
      float4 bb = *(const float4*)&Xs[k][tx * 4];
      float av[8] = {a0.x, a0.y, a0.z, a0.w, a1.x, a1.y, a1.z, a1.w};
      float bv[4] = {bb.x, bb.y, bb.z, bb.w};
#pragma unroll
      for (int i = 0; i < 8; ++i)
#pragma unroll
        for (int j = 0; j < 4; ++j)
          acc[i][j] = fmaf(av[i], bv[j], acc[i][j]);
    }
    __syncthreads();
  }

#pragma unroll
  for (int i = 0; i < 8; ++i) {
    const int o = oBase + ty * 8 + i;
    Half4 h;
#pragma unroll
    for (int j = 0; j < 4; ++j) h.v[j] = __float2half(acc[i][j]);
    *(Half4*)&Out[((size_t)b * CQKV + o) * NSP + nBase + tx * 4] = h;
  }
}

// ---------------- fused depthwise 5x5 + grouped 8x8 pointwise (fp16 in/out) ----------------
// grid: (4 tiles of 32x32, 96 groups, 16 b); block 256 threads
__global__ __launch_bounds__(256)
void dwpw_kernel(const __half* __restrict__ qkv, const float* __restrict__ wdw,
                 const float* __restrict__ wpw, __half* __restrict__ agg) {
  const int b   = blockIdx.z;
  const int gp  = blockIdx.y;
  const int ty0 = (blockIdx.x >> 1) * 32;
  const int tx0 = (blockIdx.x & 1) * 32;
  const int c0  = gp * 8;
  __shared__ float tileS[8][36][40];   // halo 2 each side, row padded to 40

  const int tid = threadIdx.x;
  const __half* src = qkv + ((size_t)b * CQKV + c0) * NSP;

#pragma unroll
  for (int ch = 0; ch < 8; ++ch) {
    for (int idx = tid; idx < 36 * 36; idx += 256) {
      const int yy = idx / 36, xx = idx - yy * 36;
      const int gy = ty0 + yy - 2, gx = tx0 + xx - 2;
      float v = 0.f;
      if (gy >= 0 && gy < 64 && gx >= 0 && gx < 64)
        v = __half2float(src[(size_t)ch * NSP + gy * 64 + gx]);
      tileS[ch][yy][xx] = v;
    }
  }
  __syncthreads();

  const int oy = tid >> 3;         // 0..31
  const int ox = (tid & 7) * 4;    // 0..28

  float dwv[8][4];
#pragma unroll
  for (int ch = 0; ch < 8; ++ch) {
    const float* wd = wdw + (size_t)(c0 + ch) * 25;
    float a0 = 0.f, a1 = 0.f, a2 = 0.f, a3 = 0.f;
#pragma unroll
    for (int dy = 0; dy < 5; ++dy) {
      float4 rA = *(const float4*)&tileS[ch][oy + dy][ox];
      float4 rB = *(const float4*)&tileS[ch][oy + dy][ox + 4];
      float r[8] = {rA.x, rA.y, rA.z, rA.w, rB.x, rB.y, rB.z, rB.w};
      const float w0 = wd[dy * 5 + 0], w1 = wd[dy * 5 + 1], w2 = wd[dy * 5 + 2],
                  w3 = wd[dy * 5 + 3], w4 = wd[dy * 5 + 4];
      a0 = fmaf(r[0], w0, a0); a0 = fmaf(r[1], w1, a0); a0 = fmaf(r[2], w2, a0);
      a0 = fmaf(r[3], w3, a0); a0 = fmaf(r[4], w4, a0);
      a1 = fmaf(r[1], w0, a1); a1 = fmaf(r[2], w1, a1); a1 = fmaf(r[3], w2, a1);
      a1 = fmaf(r[4], w3, a1); a1 = fmaf(r[5], w4, a1);
      a2 = fmaf(r[2], w0, a2); a2 = fmaf(r[3], w1, a2); a2 = fmaf(r[4], w2, a2);
      a2 = fmaf(r[5], w3, a2); a2 = fmaf(r[6], w4, a2);
      a3 = fmaf(r[3], w0, a3); a3 = fmaf(r[4], w1, a3); a3 = fmaf(r[5], w2, a3);
      a3 = fmaf(r[6], w3, a3); a3 = fmaf(r[7], w4, a3);
    }
    dwv[ch][0] = a0; dwv[ch][1] = a1; dwv[ch][2] = a2; dwv[ch][3] = a3;
  }

  const float* pwm = wpw + (size_t)gp * 64;
#pragma unroll
  for (int o = 0; o < 8; ++o) {
    float s0 = 0.f, s1 = 0.f, s2 = 0.f, s3 = 0.f;
#pragma unroll
    for (int c = 0; c < 8; ++c) {
      const float wv = pwm[o * 8 + c];
      s0 = fmaf(wv, dwv[c][0], s0);
      s1 = fmaf(wv, dwv[c][1], s1);
      s2 = fmaf(wv, dwv[c][2], s2);
      s3 = fmaf(wv, dwv[c][3], s3);
    }
    Half4 h;
    h.v[0] = __float2half(s0); h.v[1] = __float2half(s1);
    h.v[2] = __float2half(s2); h.v[3] = __float2half(s3);
    *(Half4*)&agg[((size_t)b * CQKV + c0 + o) * NSP + (ty0 + oy) * 64 + tx0 + ox] = h;
  }
}

// ---------------- attention KV matrices: kvmat[b][g][8][9] ----------------
// grid: (64 groups, 16 b); block 256 threads
__global__ __launch_bounds__(256)
void kv_kernel(const __half* __restrict__ qkv, const __half* __restrict__ agg,
               float* __restrict__ kvmat) {
  const int g = blockIdx.x;
  const int b = blockIdx.y;
  const __half* src = (g < 32)
      ? (qkv + ((size_t)b * CQKV + g * 24) * NSP)
      : (agg + ((size_t)b * CQKV + (g - 32) * 24) * NSP);
  const int tid = threadIdx.x;

  float kv[8][9];
#pragma unroll
  for (int d = 0; d < 8; ++d)
#pragma unroll
    for (int e = 0; e < 9; ++e) kv[d][e] = 0.f;

  for (int i = 0; i < 4; ++i) {
    const int n0 = i * 1024 + tid * 4;
    Half4 kh[8], vh[8];
#pragma unroll
    for (int d = 0; d < 8; ++d) kh[d] = *(const Half4*)&src[(size_t)(8 + d) * NSP + n0];
#pragma unroll
    for (int e = 0; e < 8; ++e) vh[e] = *(const Half4*)&src[(size_t)(16 + e) * NSP + n0];
#pragma unroll
    for (int j = 0; j < 4; ++j) {
      float kk[8], vv[8];
#pragma unroll
      for (int d = 0; d < 8; ++d) kk[d] = fmaxf(__half2float(kh[d].v[j]), 0.f);
#pragma unroll
      for (int e = 0; e < 8; ++e) vv[e] = __half2float(vh[e].v[j]);
#pragma unroll
      for (int d = 0; d < 8; ++d) {
#pragma unroll
        for (int e = 0; e < 8; ++e) kv[d][e] = fmaf(kk[d], vv[e], kv[d][e]);
        kv[d][8] += kk[d];
      }
    }
  }

  __shared__ float red[4][72];
  const int lane = tid & 63;
  const int wv   = tid >> 6;
#pragma unroll
  for (int d = 0; d < 8; ++d)
#pragma unroll
    for (int e = 0; e < 9; ++e) {
      float v = kv[d][e];
      v += __shfl_xor(v, 32);
      v += __shfl_xor(v, 16);
      v += __shfl_xor(v, 8);
      v += __shfl_xor(v, 4);
      v += __shfl_xor(v, 2);
      v += __shfl_xor(v, 1);
      kv[d][e] = v;
    }
  if (lane == 0) {
#pragma unroll
    for (int d = 0; d < 8; ++d)
#pragma unroll
      for (int e = 0; e < 9; ++e) red[wv][d * 9 + e] = kv[d][e];
  }
  __syncthreads();
  if (tid < 72) {
    kvmat[((size_t)b * 64 + g) * 72 + tid] =
        red[0][tid] + red[1][tid] + red[2][tid] + red[3][tid];
  }
}

// ---------------- proj GEMM with on-the-fly attention X-tile + BN ----------------
// grid: (64 n-tiles, 2 o-tiles, 16 b); block 256
__global__ __launch_bounds__(256)
void proj_kernel(const __half* __restrict__ qkv, const __half* __restrict__ agg,
                 const float* __restrict__ kvmat, const float* __restrict__ Wt,
                 float* __restrict__ Out,
                 const float* __restrict__ gamma, const float* __restrict__ beta,
                 const float* __restrict__ mean, const float* __restrict__ var) {
  const int b     = blockIdx.z;
  const int oBase = blockIdx.y * 128;
  const int nBase = blockIdx.x * 64;
  __shared__ float Ws[16][132];
  __shared__ float Xs[16][68];
  __shared__ float Qs[2][8][68];
  __shared__ float Kv[2][72];
  __shared__ float Rden[2][64];
  const int tid = threadIdx.x;
  const int tx  = tid & 15;
  const int ty  = tid >> 4;
  float acc[8][4];
#pragma unroll
  for (int i = 0; i < 8; ++i)
#pragma unroll
    for (int j = 0; j < 4; ++j) acc[i][j] = 0.f;

  for (int k0 = 0; k0 < 512; k0 += 16) {
    const int g0 = k0 >> 3;   // two attention groups per K-step
    // W tile
    {
      const int o  = tid >> 1;
      const int kk = (tid & 1) * 8;
      const float* wp = Wt + (size_t)(oBase + o) * 512 + k0 + kk;
      float4 w0 = *(const float4*)wp;
      float4 w1 = *(const float4*)(wp + 4);
      Ws[kk + 0][o] = w0.x; Ws[kk + 1][o] = w0.y;
      Ws[kk + 2][o] = w0.z; Ws[kk + 3][o] = w0.w;
      Ws[kk + 4][o] = w1.x; Ws[kk + 5][o] = w1.y;
      Ws[kk + 6][o] = w1.z; Ws[kk + 7][o] = w1.w;
    }
    // KV matrices for the two groups
    if (tid < 144) {
      const int gi = tid / 72, j = tid - gi * 72;
      Kv[gi][j] = kvmat[((size_t)b * 64 + g0 + gi) * 72 + j];
    }
    // Q tile: 2 groups x 8 d x 64 n, relu'd
    {
      const int gi = tid >> 7;
      const int rem = tid & 127;
      const int d  = rem >> 4;
      const int n4 = (rem & 15) * 4;
      const int g  = g0 + gi;
      const __half* src = (g < 32)
          ? (qkv + ((size_t)b * CQKV + g * 24) * NSP)
          : (agg + ((size_t)b * CQKV + (g - 32) * 24) * NSP);
      Half4 h = *(const Half4*)&src[(size_t)d * NSP + nBase + n4];
#pragma unroll
      for (int j = 0; j < 4; ++j)
        Qs[gi][d][n4 + j] = fmaxf(__half2float(h.v[j]), 0.f);
    }
    __syncthreads();
    // reciprocal denominators
    if (tid < 128) {
      const int gi = tid >> 6, n = tid & 63;
      float den = 0.f;
#pragma unroll
      for (int d = 0; d < 8; ++d) den = fmaf(Qs[gi][d][n], Kv[gi][d * 9 + 8], den);
      Rden[gi][n] = 1.f / (den + EPS);
    }
    __syncthreads();
    // build att X-tile
    {
      const int k  = tid >> 4;
      const int n4 = (tid & 15) * 4;
      const int gi = k >> 3;
      const int e  = k & 7;
#pragma unroll
      for (int j = 0; j < 4; ++j) {
        const int n = n4 + j;
        float num = 0.f;
#pragma unroll
        for (int d = 0; d < 8; ++d) num = fmaf(Qs[gi][d][n], Kv[gi][d * 9 + e], num);
        Xs[k][n] = num * Rden[gi][n];
      }
    }
    __syncthreads();
    // GEMM accumulate
#pragma unroll
    for (int k = 0; k < 16; ++k) {
      float4 a0 = *(const float4*)&Ws[k][ty * 8];
      float4 a1 = *(const float4*)&Ws[k][ty * 8 + 4];
      float4 bb = *(const float4*)&Xs[k][tx * 4];
      float av[8] = {a0.x, a0.y, a0.z, a0.w, a1.x, a1.y, a1.z, a1.w};
      float bv[4] = {bb.x, bb.y, bb.z, bb.w};
#pragma unroll
      for (int i = 0; i < 8; ++i)
#pragma unroll
        for (int j = 0; j < 4; ++j)
          acc[i][j] = fmaf(av[i], bv[j], acc[i][j]);
    }
    __syncthreads();
  }

#pragma unroll
  for (int i = 0; i < 8; ++i) {
    const int o = oBase + ty * 8 + i;
    const float inv  = gamma[o] / sqrtf(var[o] + 1e-5f);
    const float bias = beta[o] - mean[o] * inv;
    float4 v;
    v.x = acc[i][0] * inv + bias;
    v.y = acc[i][1] * inv + bias;
    v.z = acc[i][2] * inv + bias;
    v.w = acc[i][3] * inv + bias;
    *(float4*)&Out[((size_t)b * 256 + o) * NSP + nBase + tx * 4] = v;
  }
}

}  // namespace

extern "C" void kernel_launch(void* const* d_in, const int* in_sizes, int n_in,
                              void* d_out, int out_size, void* d_ws, size_t ws_size,
                              hipStream_t stream) {
  const float* x      = (const float*)d_in[0];
  const float* w_qkv  = (const float*)d_in[1];
  const float* w_dw   = (const float*)d_in[2];
  const float* w_pw   = (const float*)d_in[3];
  const float* w_proj = (const float*)d_in[4];
  const float* gamma  = (const float*)d_in[5];
  const float* beta   = (const float*)d_in[6];
  const float* mean   = (const float*)d_in[7];
  const float* var    = (const float*)d_in[8];
  float* out = (float*)d_out;

  const size_t nQ = (size_t)BATCH * CQKV * NSP;   // 50,331,648 elements
  __half* qkv  = (__half*)d_ws;
  __half* agg  = qkv + nQ;
  float*  kvm  = (float*)(agg + nQ);              // 16*64*72 floats

  // 1) qkv = conv1x1(x, w_qkv): O=768, K=256  (fp16 out)
  qkv_gemm_kernel<<<dim3(NSP / 64, CQKV / 128, BATCH), 256, 0, stream>>>(x, w_qkv, qkv);

  // 2) agg = grouped_pw(dw5x5(qkv))  (fp16)
  dwpw_kernel<<<dim3(4, 96, BATCH), 256, 0, stream>>>(qkv, w_dw, w_pw, agg);

  // 3) kv matrices per (b, g)
  kv_kernel<<<dim3(64, BATCH), 256, 0, stream>>>(qkv, agg, kvm);

  // 4) out = BN(conv1x1(att_on_the_fly, w_proj)): O=256, K=512
  proj_kernel<<<dim3(NSP / 64, 256 / 128, BATCH), 256, 0, stream>>>(
      qkv, agg, kvm, w_proj, out, gamma, beta, mean, var);
}

// Round 5
// 584.495 us; speedup vs baseline: 1.5714x; 1.5714x over previous
//
#include <hip/hip_runtime.h>
#include <hip/hip_fp16.h>

namespace {

constexpr int BATCH = 16;
constexpr int NSP   = 4096;   // 64*64
constexpr int CQKV  = 768;
constexpr float EPS = 1e-15f;

struct alignas(8) Half4 { __half v[4]; };

typedef _Float16 f16x8 __attribute__((ext_vector_type(8)));
typedef float f32x4 __attribute__((ext_vector_type(4)));

#define MFMA16(a, b, c) __builtin_amdgcn_mfma_f32_16x16x32_f16((a), (b), (c), 0, 0, 0)

__device__ inline f16x8 cvt8(float4 a, float4 b) {
  f16x8 r;
  r[0] = (_Float16)a.x; r[1] = (_Float16)a.y; r[2] = (_Float16)a.z; r[3] = (_Float16)a.w;
  r[4] = (_Float16)b.x; r[5] = (_Float16)b.y; r[6] = (_Float16)b.z; r[7] = (_Float16)b.w;
  return r;
}

__device__ inline void split8(const float* v, f16x8& hi, f16x8& lo) {
#pragma unroll
  for (int i = 0; i < 8; ++i) {
    _Float16 h = (_Float16)v[i];
    hi[i] = h;
    lo[i] = (_Float16)(v[i] - (float)h);
  }
}

// ---------------- pass 1: qkv = conv1x1 via split-fp16 MFMA (fp32 accuracy) ----------------
// D[o][n] 128x128, BK=32. A = w_qkv split hi/lo; B = x split hi/lo, transposed in-kernel.
// LDS [row][32] fp16 planes, 16B-block XOR swizzle slot = cb ^ ((row>>1)&3).
__global__ __launch_bounds__(256)
void qkv_mfma_kernel(const float* __restrict__ X, const float* __restrict__ Wq,
                     __half* __restrict__ qkvh) {
  const int b     = blockIdx.z;
  const int oBase = blockIdx.y * 128;
  const int nBase = blockIdx.x * 128;
  __shared__ _Float16 AsH[128 * 32];
  __shared__ _Float16 AsL[128 * 32];
  __shared__ _Float16 BsH[128 * 32];
  __shared__ _Float16 BsL[128 * 32];
  __shared__ float Xf[32][132];          // raw x tile [c][n], padded
  const int tid  = threadIdx.x;
  const int lane = tid & 63;
  const int wid  = tid >> 6;
  const int wo   = (wid >> 1) * 64;
  const int wn   = (wid & 1) * 64;

  f32x4 acc[4][4];
#pragma unroll
  for (int i = 0; i < 4; ++i)
#pragma unroll
    for (int j = 0; j < 4; ++j) acc[i][j] = {0.f, 0.f, 0.f, 0.f};

  // A staging ids
  const int r0  = tid >> 2;   // 0..63 (and +64)
  const int cb0 = tid & 3;
  const int s0  = cb0 ^ ((r0 >> 1) & 3);
  // X staging ids
  const int xc  = tid >> 3;          // 0..31
  const int xn0 = (tid & 7) * 16;    // 0..112
  // convert ids
  const int cn  = tid & 127;         // n 0..127
  const int ch  = (tid >> 7) * 16;   // c base 0 or 16
  const int cw  = (cn >> 1) & 3;

  const float* wbase = Wq + (size_t)oBase * 256;
  const float* xbase = X + (size_t)b * 256 * NSP + nBase;

  float wreg[2][8];
  float xreg[16];

  auto LOADG = [&](int t) {
    const int k0 = t * 32 + cb0 * 8;
    const float* p0 = wbase + (size_t)r0 * 256 + k0;
    *(float4*)&wreg[0][0] = *(const float4*)p0;
    *(float4*)&wreg[0][4] = *(const float4*)(p0 + 4);
    const float* p1 = wbase + (size_t)(r0 + 64) * 256 + k0;
    *(float4*)&wreg[1][0] = *(const float4*)p1;
    *(float4*)&wreg[1][4] = *(const float4*)(p1 + 4);
    const float* px = xbase + (size_t)(t * 32 + xc) * NSP + xn0;
#pragma unroll
    for (int j = 0; j < 4; ++j)
      *(float4*)&xreg[j * 4] = *(const float4*)(px + j * 4);
  };

  const int fr = lane & 15;
  const int sl = (lane >> 4) ^ ((fr >> 1) & 3);

  LOADG(0);
  for (int t = 0; t < 8; ++t) {
    // stage: split W into As planes, raw X into Xf
    {
      f16x8 h, l;
      split8(wreg[0], h, l);
      *(f16x8*)&AsH[r0 * 32 + s0 * 8] = h;
      *(f16x8*)&AsL[r0 * 32 + s0 * 8] = l;
      split8(wreg[1], h, l);
      *(f16x8*)&AsH[(r0 + 64) * 32 + s0 * 8] = h;
      *(f16x8*)&AsL[(r0 + 64) * 32 + s0 * 8] = l;
#pragma unroll
      for (int j = 0; j < 4; ++j)
        *(float4*)&Xf[xc][xn0 + j * 4] = *(const float4*)&xreg[j * 4];
    }
    __syncthreads();
    // convert: transpose-split Xf -> Bs planes
    {
      _Float16 hi[16], lo[16];
#pragma unroll
      for (int j = 0; j < 16; ++j) {
        float v = Xf[ch + j][cn];
        _Float16 h = (_Float16)v;
        hi[j] = h;
        lo[j] = (_Float16)(v - (float)h);
      }
      const int cbA = ch >> 3;               // 0 or 2
      const int sA  = cbA ^ cw;
      const int sB  = (cbA + 1) ^ cw;
      *(f16x8*)&BsH[cn * 32 + sA * 8] = *(f16x8*)&hi[0];
      *(f16x8*)&BsH[cn * 32 + sB * 8] = *(f16x8*)&hi[8];
      *(f16x8*)&BsL[cn * 32 + sA * 8] = *(f16x8*)&lo[0];
      *(f16x8*)&BsL[cn * 32 + sB * 8] = *(f16x8*)&lo[8];
    }
    __syncthreads();
    if (t < 7) LOADG(t + 1);   // global latency hides under MFMA
    f16x8 aH[4], aL[4], bH[4], bL[4];
#pragma unroll
    for (int i = 0; i < 4; ++i) {
      aH[i] = *(const f16x8*)&AsH[(wo + i * 16 + fr) * 32 + sl * 8];
      aL[i] = *(const f16x8*)&AsL[(wo + i * 16 + fr) * 32 + sl * 8];
      bH[i] = *(const f16x8*)&BsH[(wn + i * 16 + fr) * 32 + sl * 8];
      bL[i] = *(const f16x8*)&BsL[(wn + i * 16 + fr) * 32 + sl * 8];
    }
#pragma unroll
    for (int mi = 0; mi < 4; ++mi)
#pragma unroll
      for (int ni = 0; ni < 4; ++ni) {
        f32x4 a = acc[mi][ni];
        a = MFMA16(aH[mi], bH[ni], a);
        a = MFMA16(aH[mi], bL[ni], a);
        a = MFMA16(aL[mi], bH[ni], a);
        acc[mi][ni] = a;
      }
    __syncthreads();
  }

  const int orow = (lane >> 4) * 4;
  const int ncol = lane & 15;
#pragma unroll
  for (int mi = 0; mi < 4; ++mi) {
#pragma unroll
    for (int r = 0; r < 4; ++r) {
      const int o = oBase + wo + mi * 16 + orow + r;
      __half* dst = qkvh + ((size_t)b * CQKV + o) * NSP + nBase + wn + ncol;
#pragma unroll
      for (int ni = 0; ni < 4; ++ni)
        dst[ni * 16] = __float2half(acc[mi][ni][r]);
    }
  }
}

// ---------------- pass 2: fused depthwise 5x5 + grouped 8x8 pointwise (unchanged) ------------
__global__ __launch_bounds__(256)
void dwpw_kernel(const __half* __restrict__ qkv, const float* __restrict__ wdw,
                 const float* __restrict__ wpw, __half* __restrict__ agg) {
  const int b   = blockIdx.z;
  const int gp  = blockIdx.y;
  const int ty0 = (blockIdx.x >> 1) * 32;
  const int tx0 = (blockIdx.x & 1) * 32;
  const int c0  = gp * 8;
  __shared__ float tileS[8][36][40];

  const int tid = threadIdx.x;
  const __half* src = qkv + ((size_t)b * CQKV + c0) * NSP;

#pragma unroll
  for (int ch = 0; ch < 8; ++ch) {
    for (int idx = tid; idx < 36 * 36; idx += 256) {
      const int yy = idx / 36, xx = idx - yy * 36;
      const int gy = ty0 + yy - 2, gx = tx0 + xx - 2;
      float v = 0.f;
      if (gy >= 0 && gy < 64 && gx >= 0 && gx < 64)
        v = __half2float(src[(size_t)ch * NSP + gy * 64 + gx]);
      tileS[ch][yy][xx] = v;
    }
  }
  __syncthreads();

  const int oy = tid >> 3;
  const int ox = (tid & 7) * 4;

  float dwv[8][4];
#pragma unroll
  for (int ch = 0; ch < 8; ++ch) {
    const float* wd = wdw + (size_t)(c0 + ch) * 25;
    float a0 = 0.f, a1 = 0.f, a2 = 0.f, a3 = 0.f;
#pragma unroll
    for (int dy = 0; dy < 5; ++dy) {
      float4 rA = *(const float4*)&tileS[ch][oy + dy][ox];
      float4 rB = *(const float4*)&tileS[ch][oy + dy][ox + 4];
      float r[8] = {rA.x, rA.y, rA.z, rA.w, rB.x, rB.y, rB.z, rB.w};
      const float w0 = wd[dy * 5 + 0], w1 = wd[dy * 5 + 1], w2 = wd[dy * 5 + 2],
                  w3 = wd[dy * 5 + 3], w4 = wd[dy * 5 + 4];
      a0 = fmaf(r[0], w0, a0); a0 = fmaf(r[1], w1, a0); a0 = fmaf(r[2], w2, a0);
      a0 = fmaf(r[3], w3, a0); a0 = fmaf(r[4], w4, a0);
      a1 = fmaf(r[1], w0, a1); a1 = fmaf(r[2], w1, a1); a1 = fmaf(r[3], w2, a1);
      a1 = fmaf(r[4], w3, a1); a1 = fmaf(r[5], w4, a1);
      a2 = fmaf(r[2], w0, a2); a2 = fmaf(r[3], w1, a2); a2 = fmaf(r[4], w2, a2);
      a2 = fmaf(r[5], w3, a2); a2 = fmaf(r[6], w4, a2);
      a3 = fmaf(r[3], w0, a3); a3 = fmaf(r[4], w1, a3); a3 = fmaf(r[5], w2, a3);
      a3 = fmaf(r[6], w3, a3); a3 = fmaf(r[7], w4, a3);
    }
    dwv[ch][0] = a0; dwv[ch][1] = a1; dwv[ch][2] = a2; dwv[ch][3] = a3;
  }

  const float* pwm = wpw + (size_t)gp * 64;
#pragma unroll
  for (int o = 0; o < 8; ++o) {
    float s0 = 0.f, s1 = 0.f, s2 = 0.f, s3 = 0.f;
#pragma unroll
    for (int c = 0; c < 8; ++c) {
      const float wv = pwm[o * 8 + c];
      s0 = fmaf(wv, dwv[c][0], s0);
      s1 = fmaf(wv, dwv[c][1], s1);
      s2 = fmaf(wv, dwv[c][2], s2);
      s3 = fmaf(wv, dwv[c][3], s3);
    }
    Half4 h;
    h.v[0] = __float2half(s0); h.v[1] = __float2half(s1);
    h.v[2] = __float2half(s2); h.v[3] = __float2half(s3);
    *(Half4*)&agg[((size_t)b * CQKV + c0 + o) * NSP + (ty0 + oy) * 64 + tx0 + ox] = h;
  }
}

// ---------------- pass 3: attention KV matrices (unchanged) ----------------
__global__ __launch_bounds__(256)
void kv_kernel(const __half* __restrict__ qkv, const __half* __restrict__ agg,
               float* __restrict__ kvmat) {
  const int g = blockIdx.x;
  const int b = blockIdx.y;
  const __half* src = (g < 32)
      ? (qkv + ((size_t)b * CQKV + g * 24) * NSP)
      : (agg + ((size_t)b * CQKV + (g - 32) * 24) * NSP);
  const int tid = threadIdx.x;

  float kv[8][9];
#pragma unroll
  for (int d = 0; d < 8; ++d)
#pragma unroll
    for (int e = 0; e < 9; ++e) kv[d][e] = 0.f;

  for (int i = 0; i < 4; ++i) {
    const int n0 = i * 1024 + tid * 4;
    Half4 kh[8], vh[8];
#pragma unroll
    for (int d = 0; d < 8; ++d) kh[d] = *(const Half4*)&src[(size_t)(8 + d) * NSP + n0];
#pragma unroll
    for (int e = 0; e < 8; ++e) vh[e] = *(const Half4*)&src[(size_t)(16 + e) * NSP + n0];
#pragma unroll
    for (int j = 0; j < 4; ++j) {
      float kk[8], vv[8];
#pragma unroll
      for (int d = 0; d < 8; ++d) kk[d] = fmaxf(__half2float(kh[d].v[j]), 0.f);
#pragma unroll
      for (int e = 0; e < 8; ++e) vv[e] = __half2float(vh[e].v[j]);
#pragma unroll
      for (int d = 0; d < 8; ++d) {
#pragma unroll
        for (int e = 0; e < 8; ++e) kv[d][e] = fmaf(kk[d], vv[e], kv[d][e]);
        kv[d][8] += kk[d];
      }
    }
  }

  __shared__ float red[4][72];
  const int lane = tid & 63;
  const int wv   = tid >> 6;
#pragma unroll
  for (int d = 0; d < 8; ++d)
#pragma unroll
    for (int e = 0; e < 9; ++e) {
      float v = kv[d][e];
      v += __shfl_xor(v, 32);
      v += __shfl_xor(v, 16);
      v += __shfl_xor(v, 8);
      v += __shfl_xor(v, 4);
      v += __shfl_xor(v, 2);
      v += __shfl_xor(v, 1);
      kv[d][e] = v;
    }
  if (lane == 0) {
#pragma unroll
    for (int d = 0; d < 8; ++d)
#pragma unroll
      for (int e = 0; e < 9; ++e) red[wv][d * 9 + e] = kv[d][e];
  }
  __syncthreads();
  if (tid < 72) {
    kvmat[((size_t)b * 64 + g) * 72 + tid] =
        red[0][tid] + red[1][tid] + red[2][tid] + red[3][tid];
  }
}

// ---------------- pass 4: proj GEMM via MFMA fp16 with on-the-fly attention + BN -------------
__global__ __launch_bounds__(256)
void proj_mfma_kernel(const __half* __restrict__ qkvh, const __half* __restrict__ aggh,
                      const float* __restrict__ kvmat, const float* __restrict__ Wp,
                      float* __restrict__ out,
                      const float* __restrict__ gamma, const float* __restrict__ beta,
                      const float* __restrict__ mean, const float* __restrict__ var) {
  const int b     = blockIdx.z;
  const int oBase = blockIdx.y * 128;
  const int nBase = blockIdx.x * 128;
  __shared__ _Float16 As[2][128 * 32];
  __shared__ _Float16 Bs[2][128 * 32];
  __shared__ float KvS[64 * 72];
  const int tid  = threadIdx.x;
  const int lane = tid & 63;
  const int wid  = tid >> 6;
  const int wo   = (wid >> 1) * 64;
  const int wn   = (wid & 1) * 64;

  for (int i = tid; i < 64 * 72; i += 256) KvS[i] = kvmat[(size_t)b * 4608 + i];

  f32x4 acc[4][4];
#pragma unroll
  for (int i = 0; i < 4; ++i)
#pragma unroll
    for (int j = 0; j < 4; ++j) acc[i][j] = {0.f, 0.f, 0.f, 0.f};

  const int r0  = tid >> 2;
  const int cb0 = tid & 3;
  const int s0  = cb0 ^ ((r0 >> 1) & 3);
  const int np0 = tid & 127;
  const int glA = tid >> 7;
  const int glB = 2 + (tid >> 7);
  const int sbA = glA ^ ((np0 >> 1) & 3);
  const int sbB = glB ^ ((np0 >> 1) & 3);

  const float* wb = Wp + (size_t)oBase * 512;

  f16x8 ra[2];
  _Float16 qh[2][8];

  auto LOADS = [&](int t) {
    const int k0 = t * 32 + cb0 * 8;
    const float* p0 = wb + (size_t)r0 * 512 + k0;
    ra[0] = cvt8(*(const float4*)p0, *(const float4*)(p0 + 4));
    const float* p1 = wb + (size_t)(r0 + 64) * 512 + k0;
    ra[1] = cvt8(*(const float4*)p1, *(const float4*)(p1 + 4));
#pragma unroll
    for (int pi = 0; pi < 2; ++pi) {
      const int gg = t * 4 + (pi == 0 ? glA : glB);
      const __half* src = (gg < 32)
          ? (qkvh + ((size_t)b * CQKV + gg * 24) * NSP)
          : (aggh + ((size_t)b * CQKV + (gg - 32) * 24) * NSP);
      const __half* sp = src + nBase + np0;
#pragma unroll
      for (int d = 0; d < 8; ++d) qh[pi][d] = *(const _Float16*)(sp + (size_t)d * NSP);
    }
  };

  auto BUILD = [&](int t, int buf) {
    *(f16x8*)&As[buf][r0 * 32 + s0 * 8]        = ra[0];
    *(f16x8*)&As[buf][(r0 + 64) * 32 + s0 * 8] = ra[1];
#pragma unroll
    for (int pi = 0; pi < 2; ++pi) {
      const int gg = t * 4 + (pi == 0 ? glA : glB);
      const float* kv = &KvS[gg * 72];
      float q[8];
#pragma unroll
      for (int d = 0; d < 8; ++d) q[d] = fmaxf((float)qh[pi][d], 0.f);
      float den = 0.f;
#pragma unroll
      for (int d = 0; d < 8; ++d) den = fmaf(q[d], kv[d * 9 + 8], den);
      const float rden = 1.f / (den + EPS);
      f16x8 hv;
#pragma unroll
      for (int e = 0; e < 8; ++e) {
        float num = 0.f;
#pragma unroll
        for (int d = 0; d < 8; ++d) num = fmaf(q[d], kv[d * 9 + e], num);
        hv[e] = (_Float16)(num * rden);
      }
      *(f16x8*)&Bs[buf][np0 * 32 + (pi == 0 ? sbA : sbB) * 8] = hv;
    }
    __syncthreads();
  };

  const int fr = lane & 15;
  const int sl = (lane >> 4) ^ ((fr >> 1) & 3);

  LOADS(0);
  __syncthreads();   // KvS ready before first BUILD
  BUILD(0, 0);
  int cur = 0;
  for (int t = 0; t < 16; ++t) {
    if (t < 15) LOADS(t + 1);
    f16x8 af[4], bf[4];
#pragma unroll
    for (int i = 0; i < 4; ++i) {
      af[i] = *(const f16x8*)&As[cur][(wo + i * 16 + fr) * 32 + sl * 8];
      bf[i] = *(const f16x8*)&Bs[cur][(wn + i * 16 + fr) * 32 + sl * 8];
    }
#pragma unroll
    for (int mi = 0; mi < 4; ++mi)
#pragma unroll
      for (int ni = 0; ni < 4; ++ni)
        acc[mi][ni] = MFMA16(af[mi], bf[ni], acc[mi][ni]);
    if (t < 15) BUILD(t + 1, cur ^ 1);
    cur ^= 1;
  }

  const int orow = (lane >> 4) * 4;
  const int ncol = lane & 15;
#pragma unroll
  for (int mi = 0; mi < 4; ++mi) {
#pragma unroll
    for (int r = 0; r < 4; ++r) {
      const int o = oBase + wo + mi * 16 + orow + r;
      const float inv  = gamma[o] / sqrtf(var[o] + 1e-5f);
      const float bias = beta[o] - mean[o] * inv;
      float* dst = out + ((size_t)b * 256 + o) * NSP + nBase + wn + ncol;
#pragma unroll
      for (int ni = 0; ni < 4; ++ni)
        dst[ni * 16] = acc[mi][ni][r] * inv + bias;
    }
  }
}

}  // namespace

extern "C" void kernel_launch(void* const* d_in, const int* in_sizes, int n_in,
                              void* d_out, int out_size, void* d_ws, size_t ws_size,
                              hipStream_t stream) {
  const float* x      = (const float*)d_in[0];
  const float* w_qkv  = (const float*)d_in[1];
  const float* w_dw   = (const float*)d_in[2];
  const float* w_pw   = (const float*)d_in[3];
  const float* w_proj = (const float*)d_in[4];
  const float* gamma  = (const float*)d_in[5];
  const float* beta   = (const float*)d_in[6];
  const float* mean   = (const float*)d_in[7];
  const float* var    = (const float*)d_in[8];
  float* out = (float*)d_out;

  const size_t nQ = (size_t)BATCH * CQKV * NSP;   // 50,331,648 halfs
  __half* qkvh = (__half*)d_ws;
  __half* aggh = qkvh + nQ;
  float*  kvm  = (float*)(aggh + nQ);             // 16*64*72 floats

  // 1) qkv = conv1x1(x, w_qkv) via split-fp16 MFMA (fp32 accuracy)
  qkv_mfma_kernel<<<dim3(NSP / 128, CQKV / 128, BATCH), 256, 0, stream>>>(x, w_qkv, qkvh);

  // 2) agg = grouped_pw(dw5x5(qkv))
  dwpw_kernel<<<dim3(4, 96, BATCH), 256, 0, stream>>>(qkvh, w_dw, w_pw, aggh);

  // 3) kv matrices per (b, g)
  kv_kernel<<<dim3(64, BATCH), 256, 0, stream>>>(qkvh, aggh, kvm);

  // 4) out = BN(conv1x1(att_on_the_fly, w_proj)) via MFMA
  proj_mfma_kernel<<<dim3(NSP / 128, 256 / 128, BATCH), 256, 0, stream>>>(
      qkvh, aggh, kvm, w_proj, out, gamma, beta, mean, var);
}

// Round 6
// 460.545 us; speedup vs baseline: 1.9943x; 1.2691x over previous
//
#include <hip/hip_runtime.h>
#include <hip/hip_fp16.h>

namespace {

constexpr int BATCH = 16;
constexpr int NSP   = 4096;   // 64*64
constexpr int CQKV  = 768;
constexpr float EPS = 1e-15f;

struct alignas(8) Half4 { __half v[4]; };

typedef _Float16 f16x8 __attribute__((ext_vector_type(8)));
typedef _Float16 f16x2 __attribute__((ext_vector_type(2)));
typedef float f32x4 __attribute__((ext_vector_type(4)));

#define MFMA16(a, b, c) __builtin_amdgcn_mfma_f32_16x16x32_f16((a), (b), (c), 0, 0, 0)

__device__ inline f16x8 cvt8(float4 a, float4 b) {
  f16x8 r;
  r[0] = (_Float16)a.x; r[1] = (_Float16)a.y; r[2] = (_Float16)a.z; r[3] = (_Float16)a.w;
  r[4] = (_Float16)b.x; r[5] = (_Float16)b.y; r[6] = (_Float16)b.z; r[7] = (_Float16)b.w;
  return r;
}

__device__ inline void split8(const float* v, f16x8& hi, f16x8& lo) {
#pragma unroll
  for (int i = 0; i < 8; ++i) {
    _Float16 h = (_Float16)v[i];
    hi[i] = h;
    lo[i] = (_Float16)(v[i] - (float)h);
  }
}

// ---------------- pass 1: qkv = conv1x1 via split-fp16 MFMA (fp32 accuracy) ----------------
__global__ __launch_bounds__(256)
void qkv_mfma_kernel(const float* __restrict__ X, const float* __restrict__ Wq,
                     __half* __restrict__ qkvh) {
  const int b     = blockIdx.z;
  const int oBase = blockIdx.y * 128;
  const int nBase = blockIdx.x * 128;
  __shared__ _Float16 AsH[128 * 32];
  __shared__ _Float16 AsL[128 * 32];
  __shared__ _Float16 BsH[128 * 32];
  __shared__ _Float16 BsL[128 * 32];
  __shared__ float Xf[32][132];          // raw x tile [c][n], padded
  const int tid  = threadIdx.x;
  const int lane = tid & 63;
  const int wid  = tid >> 6;
  const int wo   = (wid >> 1) * 64;
  const int wn   = (wid & 1) * 64;

  f32x4 acc[4][4];
#pragma unroll
  for (int i = 0; i < 4; ++i)
#pragma unroll
    for (int j = 0; j < 4; ++j) acc[i][j] = {0.f, 0.f, 0.f, 0.f};

  const int r0  = tid >> 2;   // 0..63 (and +64)
  const int cb0 = tid & 3;
  const int s0  = cb0 ^ ((r0 >> 1) & 3);
  const int xc  = tid >> 3;          // 0..31
  const int xn0 = (tid & 7) * 16;    // 0..112
  const int cn  = tid & 127;         // n 0..127
  const int ch  = (tid >> 7) * 16;   // c base 0 or 16
  const int cw  = (cn >> 1) & 3;

  const float* wbase = Wq + (size_t)oBase * 256;
  const float* xbase = X + (size_t)b * 256 * NSP + nBase;

  float wreg[2][8];
  float xreg[16];

  auto LOADG = [&](int t) {
    const int k0 = t * 32 + cb0 * 8;
    const float* p0 = wbase + (size_t)r0 * 256 + k0;
    *(float4*)&wreg[0][0] = *(const float4*)p0;
    *(float4*)&wreg[0][4] = *(const float4*)(p0 + 4);
    const float* p1 = wbase + (size_t)(r0 + 64) * 256 + k0;
    *(float4*)&wreg[1][0] = *(const float4*)p1;
    *(float4*)&wreg[1][4] = *(const float4*)(p1 + 4);
    const float* px = xbase + (size_t)(t * 32 + xc) * NSP + xn0;
#pragma unroll
    for (int j = 0; j < 4; ++j)
      *(float4*)&xreg[j * 4] = *(const float4*)(px + j * 4);
  };

  const int fr = lane & 15;
  const int sl = (lane >> 4) ^ ((fr >> 1) & 3);

  LOADG(0);
  for (int t = 0; t < 8; ++t) {
    {
      f16x8 h, l;
      split8(wreg[0], h, l);
      *(f16x8*)&AsH[r0 * 32 + s0 * 8] = h;
      *(f16x8*)&AsL[r0 * 32 + s0 * 8] = l;
      split8(wreg[1], h, l);
      *(f16x8*)&AsH[(r0 + 64) * 32 + s0 * 8] = h;
      *(f16x8*)&AsL[(r0 + 64) * 32 + s0 * 8] = l;
#pragma unroll
      for (int j = 0; j < 4; ++j)
        *(float4*)&Xf[xc][xn0 + j * 4] = *(const float4*)&xreg[j * 4];
    }
    __syncthreads();
    {
      _Float16 hi[16], lo[16];
#pragma unroll
      for (int j = 0; j < 16; ++j) {
        float v = Xf[ch + j][cn];
        _Float16 h = (_Float16)v;
        hi[j] = h;
        lo[j] = (_Float16)(v - (float)h);
      }
      const int cbA = ch >> 3;               // 0 or 2
      const int sA  = cbA ^ cw;
      const int sB  = (cbA + 1) ^ cw;
      *(f16x8*)&BsH[cn * 32 + sA * 8] = *(f16x8*)&hi[0];
      *(f16x8*)&BsH[cn * 32 + sB * 8] = *(f16x8*)&hi[8];
      *(f16x8*)&BsL[cn * 32 + sA * 8] = *(f16x8*)&lo[0];
      *(f16x8*)&BsL[cn * 32 + sB * 8] = *(f16x8*)&lo[8];
    }
    __syncthreads();
    if (t < 7) LOADG(t + 1);   // global latency hides under MFMA
    f16x8 aH[4], aL[4], bH[4], bL[4];
#pragma unroll
    for (int i = 0; i < 4; ++i) {
      aH[i] = *(const f16x8*)&AsH[(wo + i * 16 + fr) * 32 + sl * 8];
      aL[i] = *(const f16x8*)&AsL[(wo + i * 16 + fr) * 32 + sl * 8];
      bH[i] = *(const f16x8*)&BsH[(wn + i * 16 + fr) * 32 + sl * 8];
      bL[i] = *(const f16x8*)&BsL[(wn + i * 16 + fr) * 32 + sl * 8];
    }
#pragma unroll
    for (int mi = 0; mi < 4; ++mi)
#pragma unroll
      for (int ni = 0; ni < 4; ++ni) {
        f32x4 a = acc[mi][ni];
        a = MFMA16(aH[mi], bH[ni], a);
        a = MFMA16(aH[mi], bL[ni], a);
        a = MFMA16(aL[mi], bH[ni], a);
        acc[mi][ni] = a;
      }
    __syncthreads();
  }

  const int orow = (lane >> 4) * 4;
  const int ncol = lane & 15;
#pragma unroll
  for (int mi = 0; mi < 4; ++mi) {
#pragma unroll
    for (int r = 0; r < 4; ++r) {
      const int o = oBase + wo + mi * 16 + orow + r;
      __half* dst = qkvh + ((size_t)b * CQKV + o) * NSP + nBase + wn + ncol;
#pragma unroll
      for (int ni = 0; ni < 4; ++ni)
        dst[ni * 16] = __float2half(acc[mi][ni][r]);
    }
  }
}

// ---------------- pass 2: fused depthwise 5x5 + grouped 8x8 pointwise (REWRITTEN) ------------
// tile 32 rows x 64 cols (full width), fp16 LDS [8ch][36 rows][72 halfs] + 8-half guard.
// thread = 4 rows x 2 cols x 8 ch; conflict-free ds_read_b32 window reads; pw in-register.
__global__ __launch_bounds__(256)
void dwpw_kernel(const __half* __restrict__ qkv, const float* __restrict__ wdw,
                 const float* __restrict__ wpw, __half* __restrict__ agg) {
  const int b  = blockIdx.z;
  const int gp = blockIdx.y;
  const int y0 = blockIdx.x * 32;
  const int c0 = gp * 8;
  // guard(8) + [ch][36][72]; total halfs = 8 + 8*36*72 = 20744 = 2593 quads
  __shared__ __align__(16) _Float16 tile[8 * 36 * 72 + 8];
  const int tid = threadIdx.x;

  // zero-init whole tile (guard + pads + OOB rows)
  {
    f16x8 zz = {};
    for (int i = tid; i < 2593; i += 256)
      *(f16x8*)&tile[i * 8] = zz;
  }
  __syncthreads();

  // stage valid rows: data at tile[8 + ch*2592 + tr*72 + col], col 0..63; 64..71 stay zero
#pragma unroll
  for (int chs = 0; chs < 8; ++chs) {
    const __half* src = qkv + ((size_t)b * CQKV + c0 + chs) * NSP;
    for (int i = tid; i < 288; i += 256) {
      const int tr = i >> 3, qx = i & 7;
      const int gy = y0 + tr - 2;
      if (gy >= 0 && gy < 64)
        *(f16x8*)&tile[8 + chs * 2592 + tr * 72 + qx * 8] =
            *(const f16x8*)&src[gy * 64 + qx * 8];
    }
  }
  __syncthreads();

  const int tx = tid & 31;   // col pair: cols 2tx, 2tx+1
  const int ty = tid >> 5;   // row group: rows 4ty..4ty+3

  float pwacc[8][4][2];
#pragma unroll
  for (int o = 0; o < 8; ++o)
#pragma unroll
    for (int r = 0; r < 4; ++r) { pwacc[o][r][0] = 0.f; pwacc[o][r][1] = 0.f; }

#pragma unroll
  for (int chc = 0; chc < 8; ++chc) {
    const float* wd = wdw + (size_t)(c0 + chc) * 25;
    float dwacc[4][2] = {{0.f, 0.f}, {0.f, 0.f}, {0.f, 0.f}, {0.f, 0.f}};
#pragma unroll
    for (int ir = 0; ir < 8; ++ir) {
      // window: input cols 2tx-2 .. 2tx+3 (left halo = zero pad of previous row / guard)
      const int base = 8 + chc * 2592 + (4 * ty + ir) * 72 + 2 * tx - 2;
      const f16x2* p = (const f16x2*)&tile[base];   // 4B-aligned
      f16x2 pa = p[0], pb = p[1], pc = p[2];
      float w[6];
      w[0] = (float)pa[0]; w[1] = (float)pa[1];
      w[2] = (float)pb[0]; w[3] = (float)pb[1];
      w[4] = (float)pc[0]; w[5] = (float)pc[1];
#pragma unroll
      for (int o = 0; o < 4; ++o) {
        const int dy = ir - o;
        if (dy >= 0 && dy <= 4) {
#pragma unroll
          for (int dx = 0; dx < 5; ++dx) {
            const float wv = wd[dy * 5 + dx];
            dwacc[o][0] = fmaf(w[dx],     wv, dwacc[o][0]);
            dwacc[o][1] = fmaf(w[dx + 1], wv, dwacc[o][1]);
          }
        }
      }
    }
    // grouped pointwise, accumulated on the fly
#pragma unroll
    for (int o = 0; o < 8; ++o) {
      const float pwv = wpw[(size_t)gp * 64 + o * 8 + chc];
#pragma unroll
      for (int r = 0; r < 4; ++r) {
        pwacc[o][r][0] = fmaf(pwv, dwacc[r][0], pwacc[o][r][0]);
        pwacc[o][r][1] = fmaf(pwv, dwacc[r][1], pwacc[o][r][1]);
      }
    }
  }

#pragma unroll
  for (int o = 0; o < 8; ++o) {
#pragma unroll
    for (int r = 0; r < 4; ++r) {
      __half2 hv = __floats2half2_rn(pwacc[o][r][0], pwacc[o][r][1]);
      *(__half2*)&agg[((size_t)b * CQKV + c0 + o) * NSP + (y0 + 4 * ty + r) * 64 + 2 * tx] = hv;
    }
  }
}

// ---------------- pass 3: attention KV matrices (unchanged) ----------------
__global__ __launch_bounds__(256)
void kv_kernel(const __half* __restrict__ qkv, const __half* __restrict__ agg,
               float* __restrict__ kvmat) {
  const int g = blockIdx.x;
  const int b = blockIdx.y;
  const __half* src = (g < 32)
      ? (qkv + ((size_t)b * CQKV + g * 24) * NSP)
      : (agg + ((size_t)b * CQKV + (g - 32) * 24) * NSP);
  const int tid = threadIdx.x;

  float kv[8][9];
#pragma unroll
  for (int d = 0; d < 8; ++d)
#pragma unroll
    for (int e = 0; e < 9; ++e) kv[d][e] = 0.f;

  for (int i = 0; i < 4; ++i) {
    const int n0 = i * 1024 + tid * 4;
    Half4 kh[8], vh[8];
#pragma unroll
    for (int d = 0; d < 8; ++d) kh[d] = *(const Half4*)&src[(size_t)(8 + d) * NSP + n0];
#pragma unroll
    for (int e = 0; e < 8; ++e) vh[e] = *(const Half4*)&src[(size_t)(16 + e) * NSP + n0];
#pragma unroll
    for (int j = 0; j < 4; ++j) {
      float kk[8], vv[8];
#pragma unroll
      for (int d = 0; d < 8; ++d) kk[d] = fmaxf(__half2float(kh[d].v[j]), 0.f);
#pragma unroll
      for (int e = 0; e < 8; ++e) vv[e] = __half2float(vh[e].v[j]);
#pragma unroll
      for (int d = 0; d < 8; ++d) {
#pragma unroll
        for (int e = 0; e < 8; ++e) kv[d][e] = fmaf(kk[d], vv[e], kv[d][e]);
        kv[d][8] += kk[d];
      }
    }
  }

  __shared__ float red[4][72];
  const int lane = tid & 63;
  const int wv   = tid >> 6;
#pragma unroll
  for (int d = 0; d < 8; ++d)
#pragma unroll
    for (int e = 0; e < 9; ++e) {
      float v = kv[d][e];
      v += __shfl_xor(v, 32);
      v += __shfl_xor(v, 16);
      v += __shfl_xor(v, 8);
      v += __shfl_xor(v, 4);
      v += __shfl_xor(v, 2);
      v += __shfl_xor(v, 1);
      kv[d][e] = v;
    }
  if (lane == 0) {
#pragma unroll
    for (int d = 0; d < 8; ++d)
#pragma unroll
      for (int e = 0; e < 9; ++e) red[wv][d * 9 + e] = kv[d][e];
  }
  __syncthreads();
  if (tid < 72) {
    kvmat[((size_t)b * 64 + g) * 72 + tid] =
        red[0][tid] + red[1][tid] + red[2][tid] + red[3][tid];
  }
}

// ---------------- pass 4: proj GEMM via MFMA fp16 with on-the-fly attention + BN -------------
__global__ __launch_bounds__(256)
void proj_mfma_kernel(const __half* __restrict__ qkvh, const __half* __restrict__ aggh,
                      const float* __restrict__ kvmat, const float* __restrict__ Wp,
                      float* __restrict__ out,
                      const float* __restrict__ gamma, const float* __restrict__ beta,
                      const float* __restrict__ mean, const float* __restrict__ var) {
  const int b     = blockIdx.z;
  const int oBase = blockIdx.y * 128;
  const int nBase = blockIdx.x * 128;
  __shared__ _Float16 As[2][128 * 32];
  __shared__ _Float16 Bs[2][128 * 32];
  __shared__ float KvS[64 * 72];
  const int tid  = threadIdx.x;
  const int lane = tid & 63;
  const int wid  = tid >> 6;
  const int wo   = (wid >> 1) * 64;
  const int wn   = (wid & 1) * 64;

  for (int i = tid; i < 64 * 72; i += 256) KvS[i] = kvmat[(size_t)b * 4608 + i];

  f32x4 acc[4][4];
#pragma unroll
  for (int i = 0; i < 4; ++i)
#pragma unroll
    for (int j = 0; j < 4; ++j) acc[i][j] = {0.f, 0.f, 0.f, 0.f};

  const int r0  = tid >> 2;
  const int cb0 = tid & 3;
  const int s0  = cb0 ^ ((r0 >> 1) & 3);
  const int np0 = tid & 127;
  const int glA = tid >> 7;
  const int glB = 2 + (tid >> 7);
  const int sbA = glA ^ ((np0 >> 1) & 3);
  const int sbB = glB ^ ((np0 >> 1) & 3);

  const float* wb = Wp + (size_t)oBase * 512;

  f16x8 ra[2];
  _Float16 qh[2][8];

  auto LOADS = [&](int t) {
    const int k0 = t * 32 + cb0 * 8;
    const float* p0 = wb + (size_t)r0 * 512 + k0;
    ra[0] = cvt8(*(const float4*)p0, *(const float4*)(p0 + 4));
    const float* p1 = wb + (size_t)(r0 + 64) * 512 + k0;
    ra[1] = cvt8(*(const float4*)p1, *(const float4*)(p1 + 4));
#pragma unroll
    for (int pi = 0; pi < 2; ++pi) {
      const int gg = t * 4 + (pi == 0 ? glA : glB);
      const __half* src = (gg < 32)
          ? (qkvh + ((size_t)b * CQKV + gg * 24) * NSP)
          : (aggh + ((size_t)b * CQKV + (gg - 32) * 24) * NSP);
      const __half* sp = src + nBase + np0;
#pragma unroll
      for (int d = 0; d < 8; ++d) qh[pi][d] = *(const _Float16*)(sp + (size_t)d * NSP);
    }
  };

  auto BUILD = [&](int t, int buf) {
    *(f16x8*)&As[buf][r0 * 32 + s0 * 8]        = ra[0];
    *(f16x8*)&As[buf][(r0 + 64) * 32 + s0 * 8] = ra[1];
#pragma unroll
    for (int pi = 0; pi < 2; ++pi) {
      const int gg = t * 4 + (pi == 0 ? glA : glB);
      const float* kv = &KvS[gg * 72];
      float q[8];
#pragma unroll
      for (int d = 0; d < 8; ++d) q[d] = fmaxf((float)qh[pi][d], 0.f);
      float den = 0.f;
#pragma unroll
      for (int d = 0; d < 8; ++d) den = fmaf(q[d], kv[d * 9 + 8], den);
      const float rden = 1.f / (den + EPS);
      f16x8 hv;
#pragma unroll
      for (int e = 0; e < 8; ++e) {
        float num = 0.f;
#pragma unroll
        for (int d = 0; d < 8; ++d) num = fmaf(q[d], kv[d * 9 + e], num);
        hv[e] = (_Float16)(num * rden);
      }
      *(f16x8*)&Bs[buf][np0 * 32 + (pi == 0 ? sbA : sbB) * 8] = hv;
    }
    __syncthreads();
  };

  const int fr = lane & 15;
  const int sl = (lane >> 4) ^ ((fr >> 1) & 3);

  LOADS(0);
  __syncthreads();   // KvS ready before first BUILD
  BUILD(0, 0);
  int cur = 0;
  for (int t = 0; t < 16; ++t) {
    if (t < 15) LOADS(t + 1);
    f16x8 af[4], bf[4];
#pragma unroll
    for (int i = 0; i < 4; ++i) {
      af[i] = *(const f16x8*)&As[cur][(wo + i * 16 + fr) * 32 + sl * 8];
      bf[i] = *(const f16x8*)&Bs[cur][(wn + i * 16 + fr) * 32 + sl * 8];
    }
#pragma unroll
    for (int mi = 0; mi < 4; ++mi)
#pragma unroll
      for (int ni = 0; ni < 4; ++ni)
        acc[mi][ni] = MFMA16(af[mi], bf[ni], acc[mi][ni]);
    if (t < 15) BUILD(t + 1, cur ^ 1);
    cur ^= 1;
  }

  const int orow = (lane >> 4) * 4;
  const int ncol = lane & 15;
#pragma unroll
  for (int mi = 0; mi < 4; ++mi) {
#pragma unroll
    for (int r = 0; r < 4; ++r) {
      const int o = oBase + wo + mi * 16 + orow + r;
      const float inv  = gamma[o] / sqrtf(var[o] + 1e-5f);
      const float bias = beta[o] - mean[o] * inv;
      float* dst = out + ((size_t)b * 256 + o) * NSP + nBase + wn + ncol;
#pragma unroll
      for (int ni = 0; ni < 4; ++ni)
        dst[ni * 16] = acc[mi][ni][r] * inv + bias;
    }
  }
}

}  // namespace

extern "C" void kernel_launch(void* const* d_in, const int* in_sizes, int n_in,
                              void* d_out, int out_size, void* d_ws, size_t ws_size,
                              hipStream_t stream) {
  const float* x      = (const float*)d_in[0];
  const float* w_qkv  = (const float*)d_in[1];
  const float* w_dw   = (const float*)d_in[2];
  const float* w_pw   = (const float*)d_in[3];
  const float* w_proj = (const float*)d_in[4];
  const float* gamma  = (const float*)d_in[5];
  const float* beta   = (const float*)d_in[6];
  const float* mean   = (const float*)d_in[7];
  const float* var    = (const float*)d_in[8];
  float* out = (float*)d_out;

  const size_t nQ = (size_t)BATCH * CQKV * NSP;   // 50,331,648 halfs
  __half* qkvh = (__half*)d_ws;
  __half* aggh = qkvh + nQ;
  float*  kvm  = (float*)(aggh + nQ);             // 16*64*72 floats

  // 1) qkv = conv1x1(x, w_qkv) via split-fp16 MFMA (fp32 accuracy)
  qkv_mfma_kernel<<<dim3(NSP / 128, CQKV / 128, BATCH), 256, 0, stream>>>(x, w_qkv, qkvh);

  // 2) agg = grouped_pw(dw5x5(qkv))  — rewritten: conflict-free b32 reads, fp16 tile
  dwpw_kernel<<<dim3(2, 96, BATCH), 256, 0, stream>>>(qkvh, w_dw, w_pw, aggh);

  // 3) kv matrices per (b, g)
  kv_kernel<<<dim3(64, BATCH), 256, 0, stream>>>(qkvh, aggh, kvm);

  // 4) out = BN(conv1x1(att_on_the_fly, w_proj)) via MFMA
  proj_mfma_kernel<<<dim3(NSP / 128, 256 / 128, BATCH), 256, 0, stream>>>(
      qkvh, aggh, kvm, w_proj, out, gamma, beta, mean, var);
}

// Round 7
// 405.229 us; speedup vs baseline: 2.2665x; 1.1365x over previous
//
#include <hip/hip_runtime.h>
#include <hip/hip_fp16.h>

namespace {

constexpr int BATCH = 16;
constexpr int NSP   = 4096;   // 64*64
constexpr int CQKV  = 768;
constexpr float EPS = 1e-15f;

struct alignas(8) Half4 { __half v[4]; };

typedef _Float16 f16x8 __attribute__((ext_vector_type(8)));
typedef float f32x4 __attribute__((ext_vector_type(4)));

#define MFMA16(a, b, c) __builtin_amdgcn_mfma_f32_16x16x32_f16((a), (b), (c), 0, 0, 0)

__device__ inline f16x8 cvt8(float4 a, float4 b) {
  f16x8 r;
  r[0] = (_Float16)a.x; r[1] = (_Float16)a.y; r[2] = (_Float16)a.z; r[3] = (_Float16)a.w;
  r[4] = (_Float16)b.x; r[5] = (_Float16)b.y; r[6] = (_Float16)b.z; r[7] = (_Float16)b.w;
  return r;
}

__device__ inline void gload16(const void* g, void* l) {
  __builtin_amdgcn_global_load_lds(
      (const __attribute__((address_space(1))) void*)g,
      (__attribute__((address_space(3))) void*)l, 16, 0, 0);
}

// ---------------- pass 0a: x [b][256][4096] f32 -> xtH/xtL [b][4096][256] fp16, pre-swizzled --
// storage permutation within each 32-half k-group: block cb stored at slot cb ^ ((n>>1)&3)
__global__ __launch_bounds__(256)
void xprep_kernel(const float* __restrict__ x, _Float16* __restrict__ xh,
                  _Float16* __restrict__ xl) {
  const int b  = blockIdx.z;
  const int c0 = blockIdx.y * 64;
  const int n0 = blockIdx.x * 64;
  __shared__ float T[64][65];
  const int tid = threadIdx.x;
  const int cl  = tid >> 4;            // 0..15
  const int n4  = (tid & 15) * 4;
  const float* xb = x + ((size_t)b * 256 + c0) * NSP + n0;
#pragma unroll
  for (int i = 0; i < 4; ++i) {
    const int c = cl + i * 16;
    float4 v = *(const float4*)&xb[(size_t)c * NSP + n4];
    T[n4 + 0][c] = v.x; T[n4 + 1][c] = v.y; T[n4 + 2][c] = v.z; T[n4 + 3][c] = v.w;
  }
  __syncthreads();
  const int n   = tid >> 2;            // local n 0..63
  const int cb  = (tid & 3) * 16;      // local c start
  const int ng  = n0 + n;
  const int swz = (ng >> 1) & 3;
  _Float16 hi[16], lo[16];
#pragma unroll
  for (int j = 0; j < 16; ++j) {
    float v = T[n][cb + j];
    _Float16 h = (_Float16)v;
    hi[j] = h;
    lo[j] = (_Float16)(v - (float)h);
  }
  const int cg  = c0 + cb;             // global c start (multiple of 16)
  const int grp = cg >> 5;
  const int b0  = (cg >> 3) & 3;       // 0 or 2
  const int s0  = b0 ^ swz;
  const int s1  = (b0 + 1) ^ swz;
  _Float16* dh = xh + ((size_t)b * NSP + ng) * 256 + grp * 32;
  _Float16* dl = xl + ((size_t)b * NSP + ng) * 256 + grp * 32;
  *(f16x8*)&dh[s0 * 8] = *(f16x8*)&hi[0];
  *(f16x8*)&dh[s1 * 8] = *(f16x8*)&hi[8];
  *(f16x8*)&dl[s0 * 8] = *(f16x8*)&lo[0];
  *(f16x8*)&dl[s1 * 8] = *(f16x8*)&lo[8];
}

// ---------------- pass 0b: w_qkv [768][256] f32 -> wH/wL fp16, pre-swizzled by o-row ---------
__global__ __launch_bounds__(256)
void wprep_kernel(const float* __restrict__ w, _Float16* __restrict__ wh,
                  _Float16* __restrict__ wl) {
  const int o = blockIdx.x;
  const int c = threadIdx.x;
  float v = w[(size_t)o * 256 + c];
  _Float16 h = (_Float16)v;
  _Float16 l = (_Float16)(v - (float)h);
  const int swz = (o >> 1) & 3;
  const int pos = (c >> 5) * 32 + (((c >> 3) & 3) ^ swz) * 8 + (c & 7);
  wh[(size_t)o * 256 + pos] = h;
  wl[(size_t)o * 256 + pos] = l;
}

// ---------------- pass 1: qkv = conv1x1 via split-fp16 MFMA, global_load_lds staging --------
// D[o][n] 128x128, BK=32; planes [AH][AL][BH][BL] 8KB each, single-buffered, 2 barriers/step.
__global__ __launch_bounds__(256, 4)
void qkv_mfma_kernel(const _Float16* __restrict__ xh, const _Float16* __restrict__ xl,
                     const _Float16* __restrict__ wh, const _Float16* __restrict__ wl,
                     __half* __restrict__ qkvh) {
  const int b     = blockIdx.z;
  const int oBase = blockIdx.y * 128;
  const int nBase = blockIdx.x * 128;
  // 4 planes x 4096 halfs (32KB) + epilogue needs 128*136 halfs (34KB) -> 17408 halfs
  __shared__ __align__(16) _Float16 S[17408];
  const int tid  = threadIdx.x;
  const int lane = tid & 63;
  const int wid  = tid >> 6;
  const int wo   = (wid >> 1) * 64;
  const int wn   = (wid & 1) * 64;

  f32x4 acc[4][4];
#pragma unroll
  for (int i = 0; i < 4; ++i)
#pragma unroll
    for (int j = 0; j < 4; ++j) acc[i][j] = {0.f, 0.f, 0.f, 0.f};

  // wave wid stages plane wid: 0=AH 1=AL 2=BH 3=BL
  const _Float16* sb =
      (wid == 0) ? wh + (size_t)oBase * 256 :
      (wid == 1) ? wl + (size_t)oBase * 256 :
      (wid == 2) ? xh + ((size_t)b * NSP + nBase) * 256 :
                   xl + ((size_t)b * NSP + nBase) * 256;
  const _Float16* lanesrc = sb + (size_t)(lane >> 2) * 256 + (lane & 3) * 8;
  _Float16* plane = S + wid * 4096;

  const int fr = lane & 15;
  const int sl = (lane >> 4) ^ ((fr >> 1) & 3);

  for (int t = 0; t < 8; ++t) {
    // stage step t (linear copy of pre-swizzled source)
    const _Float16* ls = lanesrc + t * 32;
#pragma unroll
    for (int i = 0; i < 8; ++i)
      gload16(ls + (size_t)i * 16 * 256, plane + i * 512);
    __syncthreads();   // drains vmcnt(0)

    f16x8 bHf[4], bLf[4];
#pragma unroll
    for (int i = 0; i < 4; ++i) {
      bHf[i] = *(const f16x8*)&S[2 * 4096 + (wn + i * 16 + fr) * 32 + sl * 8];
      bLf[i] = *(const f16x8*)&S[3 * 4096 + (wn + i * 16 + fr) * 32 + sl * 8];
    }
#pragma unroll
    for (int mi = 0; mi < 4; ++mi) {
      f16x8 aHf = *(const f16x8*)&S[0 * 4096 + (wo + mi * 16 + fr) * 32 + sl * 8];
      f16x8 aLf = *(const f16x8*)&S[1 * 4096 + (wo + mi * 16 + fr) * 32 + sl * 8];
#pragma unroll
      for (int ni = 0; ni < 4; ++ni) {
        f32x4 a = acc[mi][ni];
        a = MFMA16(aHf, bHf[ni], a);
        a = MFMA16(aHf, bLf[ni], a);
        a = MFMA16(aLf, bHf[ni], a);
        acc[mi][ni] = a;
      }
    }
    __syncthreads();   // reads done before next-step overwrite
  }

  // epilogue: LDS bounce (stride 136 to spread banks), then coalesced 16B stores
  const int orow = (lane >> 4) * 4;
  const int ncol = lane & 15;
#pragma unroll
  for (int mi = 0; mi < 4; ++mi)
#pragma unroll
    for (int ni = 0; ni < 4; ++ni)
#pragma unroll
      for (int r = 0; r < 4; ++r)
        S[(wo + mi * 16 + orow + r) * 136 + wn + ncol + ni * 16] =
            (_Float16)acc[mi][ni][r];
  __syncthreads();
  _Float16* qk = (_Float16*)qkvh;
#pragma unroll
  for (int j = 0; j < 8; ++j) {
    const int c   = j * 256 + tid;     // 16B chunk id 0..2047
    const int row = c >> 4;
    const int blk = c & 15;
    *(f16x8*)&qk[((size_t)b * CQKV + oBase + row) * NSP + nBase + blk * 8] =
        *(const f16x8*)&S[row * 136 + blk * 8];
  }
}

// ---------------- pass 2: fused depthwise 5x5 + grouped 8x8 pointwise (unchanged) ------------
__global__ __launch_bounds__(256)
void dwpw_kernel(const __half* __restrict__ qkv, const float* __restrict__ wdw,
                 const float* __restrict__ wpw, __half* __restrict__ agg) {
  const int b  = blockIdx.z;
  const int gp = blockIdx.y;
  const int y0 = blockIdx.x * 32;
  const int c0 = gp * 8;
  __shared__ __align__(16) _Float16 tile[8 * 36 * 72 + 8];
  const int tid = threadIdx.x;

  {
    f16x8 zz = {};
    for (int i = tid; i < 2593; i += 256)
      *(f16x8*)&tile[i * 8] = zz;
  }
  __syncthreads();

#pragma unroll
  for (int chs = 0; chs < 8; ++chs) {
    const __half* src = qkv + ((size_t)b * CQKV + c0 + chs) * NSP;
    for (int i = tid; i < 288; i += 256) {
      const int tr = i >> 3, qx = i & 7;
      const int gy = y0 + tr - 2;
      if (gy >= 0 && gy < 64)
        *(f16x8*)&tile[8 + chs * 2592 + tr * 72 + qx * 8] =
            *(const f16x8*)&src[gy * 64 + qx * 8];
    }
  }
  __syncthreads();

  const int tx = tid & 31;
  const int ty = tid >> 5;

  float pwacc[8][4][2];
#pragma unroll
  for (int o = 0; o < 8; ++o)
#pragma unroll
    for (int r = 0; r < 4; ++r) { pwacc[o][r][0] = 0.f; pwacc[o][r][1] = 0.f; }

  typedef _Float16 f16x2 __attribute__((ext_vector_type(2)));
#pragma unroll
  for (int chc = 0; chc < 8; ++chc) {
    const float* wd = wdw + (size_t)(c0 + chc) * 25;
    float dwacc[4][2] = {{0.f, 0.f}, {0.f, 0.f}, {0.f, 0.f}, {0.f, 0.f}};
#pragma unroll
    for (int ir = 0; ir < 8; ++ir) {
      const int base = 8 + chc * 2592 + (4 * ty + ir) * 72 + 2 * tx - 2;
      const f16x2* p = (const f16x2*)&tile[base];
      f16x2 pa = p[0], pb = p[1], pc = p[2];
      float w[6];
      w[0] = (float)pa[0]; w[1] = (float)pa[1];
      w[2] = (float)pb[0]; w[3] = (float)pb[1];
      w[4] = (float)pc[0]; w[5] = (float)pc[1];
#pragma unroll
      for (int o = 0; o < 4; ++o) {
        const int dy = ir - o;
        if (dy >= 0 && dy <= 4) {
#pragma unroll
          for (int dx = 0; dx < 5; ++dx) {
            const float wv = wd[dy * 5 + dx];
            dwacc[o][0] = fmaf(w[dx],     wv, dwacc[o][0]);
            dwacc[o][1] = fmaf(w[dx + 1], wv, dwacc[o][1]);
          }
        }
      }
    }
#pragma unroll
    for (int o = 0; o < 8; ++o) {
      const float pwv = wpw[(size_t)gp * 64 + o * 8 + chc];
#pragma unroll
      for (int r = 0; r < 4; ++r) {
        pwacc[o][r][0] = fmaf(pwv, dwacc[r][0], pwacc[o][r][0]);
        pwacc[o][r][1] = fmaf(pwv, dwacc[r][1], pwacc[o][r][1]);
      }
    }
  }

#pragma unroll
  for (int o = 0; o < 8; ++o) {
#pragma unroll
    for (int r = 0; r < 4; ++r) {
      __half2 hv = __floats2half2_rn(pwacc[o][r][0], pwacc[o][r][1]);
      *(__half2*)&agg[((size_t)b * CQKV + c0 + o) * NSP + (y0 + 4 * ty + r) * 64 + 2 * tx] = hv;
    }
  }
}

// ---------------- pass 3: attention KV matrices (unchanged) ----------------
__global__ __launch_bounds__(256)
void kv_kernel(const __half* __restrict__ qkv, const __half* __restrict__ agg,
               float* __restrict__ kvmat) {
  const int g = blockIdx.x;
  const int b = blockIdx.y;
  const __half* src = (g < 32)
      ? (qkv + ((size_t)b * CQKV + g * 24) * NSP)
      : (agg + ((size_t)b * CQKV + (g - 32) * 24) * NSP);
  const int tid = threadIdx.x;

  float kv[8][9];
#pragma unroll
  for (int d = 0; d < 8; ++d)
#pragma unroll
    for (int e = 0; e < 9; ++e) kv[d][e] = 0.f;

  for (int i = 0; i < 4; ++i) {
    const int n0 = i * 1024 + tid * 4;
    Half4 kh[8], vh[8];
#pragma unroll
    for (int d = 0; d < 8; ++d) kh[d] = *(const Half4*)&src[(size_t)(8 + d) * NSP + n0];
#pragma unroll
    for (int e = 0; e < 8; ++e) vh[e] = *(const Half4*)&src[(size_t)(16 + e) * NSP + n0];
#pragma unroll
    for (int j = 0; j < 4; ++j) {
      float kk[8], vv[8];
#pragma unroll
      for (int d = 0; d < 8; ++d) kk[d] = fmaxf(__half2float(kh[d].v[j]), 0.f);
#pragma unroll
      for (int e = 0; e < 8; ++e) vv[e] = __half2float(vh[e].v[j]);
#pragma unroll
      for (int d = 0; d < 8; ++d) {
#pragma unroll
        for (int e = 0; e < 8; ++e) kv[d][e] = fmaf(kk[d], vv[e], kv[d][e]);
        kv[d][8] += kk[d];
      }
    }
  }

  __shared__ float red[4][72];
  const int lane = tid & 63;
  const int wv   = tid >> 6;
#pragma unroll
  for (int d = 0; d < 8; ++d)
#pragma unroll
    for (int e = 0; e < 9; ++e) {
      float v = kv[d][e];
      v += __shfl_xor(v, 32);
      v += __shfl_xor(v, 16);
      v += __shfl_xor(v, 8);
      v += __shfl_xor(v, 4);
      v += __shfl_xor(v, 2);
      v += __shfl_xor(v, 1);
      kv[d][e] = v;
    }
  if (lane == 0) {
#pragma unroll
    for (int d = 0; d < 8; ++d)
#pragma unroll
      for (int e = 0; e < 9; ++e) red[wv][d * 9 + e] = kv[d][e];
  }
  __syncthreads();
  if (tid < 72) {
    kvmat[((size_t)b * 64 + g) * 72 + tid] =
        red[0][tid] + red[1][tid] + red[2][tid] + red[3][tid];
  }
}

// ---------------- pass 4: proj GEMM via MFMA fp16 with on-the-fly attention + BN -------------
__global__ __launch_bounds__(256)
void proj_mfma_kernel(const __half* __restrict__ qkvh, const __half* __restrict__ aggh,
                      const float* __restrict__ kvmat, const float* __restrict__ Wp,
                      float* __restrict__ out,
                      const float* __restrict__ gamma, const float* __restrict__ beta,
                      const float* __restrict__ mean, const float* __restrict__ var) {
  const int b     = blockIdx.z;
  const int oBase = blockIdx.y * 128;
  const int nBase = blockIdx.x * 128;
  __shared__ _Float16 As[2][128 * 32];
  __shared__ _Float16 Bs[2][128 * 32];
  __shared__ float KvS[64 * 72];
  const int tid  = threadIdx.x;
  const int lane = tid & 63;
  const int wid  = tid >> 6;
  const int wo   = (wid >> 1) * 64;
  const int wn   = (wid & 1) * 64;

  for (int i = tid; i < 64 * 72; i += 256) KvS[i] = kvmat[(size_t)b * 4608 + i];

  f32x4 acc[4][4];
#pragma unroll
  for (int i = 0; i < 4; ++i)
#pragma unroll
    for (int j = 0; j < 4; ++j) acc[i][j] = {0.f, 0.f, 0.f, 0.f};

  const int r0  = tid >> 2;
  const int cb0 = tid & 3;
  const int s0  = cb0 ^ ((r0 >> 1) & 3);
  const int np0 = tid & 127;
  const int glA = tid >> 7;
  const int glB = 2 + (tid >> 7);
  const int sbA = glA ^ ((np0 >> 1) & 3);
  const int sbB = glB ^ ((np0 >> 1) & 3);

  const float* wb = Wp + (size_t)oBase * 512;

  f16x8 ra[2];
  _Float16 qh[2][8];

  auto LOADS = [&](int t) {
    const int k0 = t * 32 + cb0 * 8;
    const float* p0 = wb + (size_t)r0 * 512 + k0;
    ra[0] = cvt8(*(const float4*)p0, *(const float4*)(p0 + 4));
    const float* p1 = wb + (size_t)(r0 + 64) * 512 + k0;
    ra[1] = cvt8(*(const float4*)p1, *(const float4*)(p1 + 4));
#pragma unroll
    for (int pi = 0; pi < 2; ++pi) {
      const int gg = t * 4 + (pi == 0 ? glA : glB);
      const __half* src = (gg < 32)
          ? (qkvh + ((size_t)b * CQKV + gg * 24) * NSP)
          : (aggh + ((size_t)b * CQKV + (gg - 32) * 24) * NSP);
      const __half* sp = src + nBase + np0;
#pragma unroll
      for (int d = 0; d < 8; ++d) qh[pi][d] = *(const _Float16*)(sp + (size_t)d * NSP);
    }
  };

  auto BUILD = [&](int t, int buf) {
    *(f16x8*)&As[buf][r0 * 32 + s0 * 8]        = ra[0];
    *(f16x8*)&As[buf][(r0 + 64) * 32 + s0 * 8] = ra[1];
#pragma unroll
    for (int pi = 0; pi < 2; ++pi) {
      const int gg = t * 4 + (pi == 0 ? glA : glB);
      const float* kv = &KvS[gg * 72];
      float q[8];
#pragma unroll
      for (int d = 0; d < 8; ++d) q[d] = fmaxf((float)qh[pi][d], 0.f);
      float den = 0.f;
#pragma unroll
      for (int d = 0; d < 8; ++d) den = fmaf(q[d], kv[d * 9 + 8], den);
      const float rden = 1.f / (den + EPS);
      f16x8 hv;
#pragma unroll
      for (int e = 0; e < 8; ++e) {
        float num = 0.f;
#pragma unroll
        for (int d = 0; d < 8; ++d) num = fmaf(q[d], kv[d * 9 + e], num);
        hv[e] = (_Float16)(num * rden);
      }
      *(f16x8*)&Bs[buf][np0 * 32 + (pi == 0 ? sbA : sbB) * 8] = hv;
    }
    __syncthreads();
  };

  const int fr = lane & 15;
  const int sl = (lane >> 4) ^ ((fr >> 1) & 3);

  LOADS(0);
  __syncthreads();   // KvS ready before first BUILD
  BUILD(0, 0);
  int cur = 0;
  for (int t = 0; t < 16; ++t) {
    if (t < 15) LOADS(t + 1);
    f16x8 af[4], bf[4];
#pragma unroll
    for (int i = 0; i < 4; ++i) {
      af[i] = *(const f16x8*)&As[cur][(wo + i * 16 + fr) * 32 + sl * 8];
      bf[i] = *(const f16x8*)&Bs[cur][(wn + i * 16 + fr) * 32 + sl * 8];
    }
#pragma unroll
    for (int mi = 0; mi < 4; ++mi)
#pragma unroll
      for (int ni = 0; ni < 4; ++ni)
        acc[mi][ni] = MFMA16(af[mi], bf[ni], acc[mi][ni]);
    if (t < 15) BUILD(t + 1, cur ^ 1);
    cur ^= 1;
  }

  const int orow = (lane >> 4) * 4;
  const int ncol = lane & 15;
#pragma unroll
  for (int mi = 0; mi < 4; ++mi) {
#pragma unroll
    for (int r = 0; r < 4; ++r) {
      const int o = oBase + wo + mi * 16 + orow + r;
      const float inv  = gamma[o] / sqrtf(var[o] + 1e-5f);
      const float bias = beta[o] - mean[o] * inv;
      float* dst = out + ((size_t)b * 256 + o) * NSP + nBase + wn + ncol;
#pragma unroll
      for (int ni = 0; ni < 4; ++ni)
        dst[ni * 16] = acc[mi][ni][r] * inv + bias;
    }
  }
}

}  // namespace

extern "C" void kernel_launch(void* const* d_in, const int* in_sizes, int n_in,
                              void* d_out, int out_size, void* d_ws, size_t ws_size,
                              hipStream_t stream) {
  const float* x      = (const float*)d_in[0];
  const float* w_qkv  = (const float*)d_in[1];
  const float* w_dw   = (const float*)d_in[2];
  const float* w_pw   = (const float*)d_in[3];
  const float* w_proj = (const float*)d_in[4];
  const float* gamma  = (const float*)d_in[5];
  const float* beta   = (const float*)d_in[6];
  const float* mean   = (const float*)d_in[7];
  const float* var    = (const float*)d_in[8];
  float* out = (float*)d_out;

  const size_t nQ = (size_t)BATCH * CQKV * NSP;   // 50,331,648 halfs (96 MiB)
  __half* qkvh = (__half*)d_ws;
  __half* aggh = qkvh + nQ;
  float*  kvm  = (float*)(aggh + nQ);             // 16*64*72 floats

  // x/w split planes alias the agg region (dead until dwpw writes it):
  const size_t nX = (size_t)BATCH * NSP * 256;    // 16,777,216 halfs per plane
  _Float16* xtH = (_Float16*)aggh;
  _Float16* xtL = xtH + nX;
  _Float16* wH  = xtL + nX;                       // 768*256 halfs
  _Float16* wL  = wH + (size_t)CQKV * 256;        // total alias 64.75 MiB < 96 MiB

  // 0) prep: transpose+split x (pre-swizzled), split w_qkv (pre-swizzled)
  xprep_kernel<<<dim3(64, 4, BATCH), 256, 0, stream>>>(x, xtH, xtL);
  wprep_kernel<<<dim3(CQKV), 256, 0, stream>>>(w_qkv, wH, wL);

  // 1) qkv = conv1x1(x, w_qkv) via split-fp16 MFMA + global_load_lds
  qkv_mfma_kernel<<<dim3(NSP / 128, CQKV / 128, BATCH), 256, 0, stream>>>(
      xtH, xtL, wH, wL, qkvh);

  // 2) agg = grouped_pw(dw5x5(qkv))
  dwpw_kernel<<<dim3(2, 96, BATCH), 256, 0, stream>>>(qkvh, w_dw, w_pw, aggh);

  // 3) kv matrices per (b, g)
  kv_kernel<<<dim3(64, BATCH), 256, 0, stream>>>(qkvh, aggh, kvm);

  // 4) out = BN(conv1x1(att_on_the_fly, w_proj)) via MFMA
  proj_mfma_kernel<<<dim3(NSP / 128, 256 / 128, BATCH), 256, 0, stream>>>(
      qkvh, aggh, kvm, w_proj, out, gamma, beta, mean, var);
}

// Round 8
// 387.223 us; speedup vs baseline: 2.3719x; 1.0465x over previous
//
#include <hip/hip_runtime.h>
#include <hip/hip_fp16.h>

namespace {

constexpr int BATCH = 16;
constexpr int NSP   = 4096;   // 64*64
constexpr int CQKV  = 768;
constexpr float EPS = 1e-15f;

struct alignas(8) Half4 { __half v[4]; };

typedef _Float16 f16x8 __attribute__((ext_vector_type(8)));
typedef float f32x4 __attribute__((ext_vector_type(4)));

#define MFMA16(a, b, c) __builtin_amdgcn_mfma_f32_16x16x32_f16((a), (b), (c), 0, 0, 0)

__device__ inline f16x8 cvt8(float4 a, float4 b) {
  f16x8 r;
  r[0] = (_Float16)a.x; r[1] = (_Float16)a.y; r[2] = (_Float16)a.z; r[3] = (_Float16)a.w;
  r[4] = (_Float16)b.x; r[5] = (_Float16)b.y; r[6] = (_Float16)b.z; r[7] = (_Float16)b.w;
  return r;
}

__device__ inline void gload16(const void* g, void* l) {
  __builtin_amdgcn_global_load_lds(
      (const __attribute__((address_space(1))) void*)g,
      (__attribute__((address_space(3))) void*)l, 16, 0, 0);
}

// ---------------- pass 0a: x [b][256][4096] f32 -> xtH/xtL [b][4096][256] fp16, pre-swizzled --
__global__ __launch_bounds__(256)
void xprep_kernel(const float* __restrict__ x, _Float16* __restrict__ xh,
                  _Float16* __restrict__ xl) {
  const int b  = blockIdx.z;
  const int c0 = blockIdx.y * 64;
  const int n0 = blockIdx.x * 64;
  __shared__ float T[64][65];
  const int tid = threadIdx.x;
  const int cl  = tid >> 4;
  const int n4  = (tid & 15) * 4;
  const float* xb = x + ((size_t)b * 256 + c0) * NSP + n0;
#pragma unroll
  for (int i = 0; i < 4; ++i) {
    const int c = cl + i * 16;
    float4 v = *(const float4*)&xb[(size_t)c * NSP + n4];
    T[n4 + 0][c] = v.x; T[n4 + 1][c] = v.y; T[n4 + 2][c] = v.z; T[n4 + 3][c] = v.w;
  }
  __syncthreads();
  const int n   = tid >> 2;
  const int cb  = (tid & 3) * 16;
  const int ng  = n0 + n;
  const int swz = (ng >> 1) & 3;
  _Float16 hi[16], lo[16];
#pragma unroll
  for (int j = 0; j < 16; ++j) {
    float v = T[n][cb + j];
    _Float16 h = (_Float16)v;
    hi[j] = h;
    lo[j] = (_Float16)(v - (float)h);
  }
  const int cg  = c0 + cb;
  const int grp = cg >> 5;
  const int b0  = (cg >> 3) & 3;
  const int s0  = b0 ^ swz;
  const int s1  = (b0 + 1) ^ swz;
  _Float16* dh = xh + ((size_t)b * NSP + ng) * 256 + grp * 32;
  _Float16* dl = xl + ((size_t)b * NSP + ng) * 256 + grp * 32;
  *(f16x8*)&dh[s0 * 8] = *(f16x8*)&hi[0];
  *(f16x8*)&dh[s1 * 8] = *(f16x8*)&hi[8];
  *(f16x8*)&dl[s0 * 8] = *(f16x8*)&lo[0];
  *(f16x8*)&dl[s1 * 8] = *(f16x8*)&lo[8];
}

// ---------------- pass 0b: w_qkv split fp16, pre-swizzled by o-row ----------------
__global__ __launch_bounds__(256)
void wprep_kernel(const float* __restrict__ w, _Float16* __restrict__ wh,
                  _Float16* __restrict__ wl) {
  const int o = blockIdx.x;
  const int c = threadIdx.x;
  float v = w[(size_t)o * 256 + c];
  _Float16 h = (_Float16)v;
  _Float16 l = (_Float16)(v - (float)h);
  const int swz = (o >> 1) & 3;
  const int pos = (c >> 5) * 32 + (((c >> 3) & 3) ^ swz) * 8 + (c & 7);
  wh[(size_t)o * 256 + pos] = h;
  wl[(size_t)o * 256 + pos] = l;
}

// ---------------- pass 0c: w_proj [256][512] f32 -> fp16, pre-swizzled by o-row --------------
__global__ __launch_bounds__(256)
void wprep2_kernel(const float* __restrict__ w, _Float16* __restrict__ wp) {
  const int o = blockIdx.x;
  const int swz = (o >> 1) & 3;
#pragma unroll
  for (int i = 0; i < 2; ++i) {
    const int c = threadIdx.x + i * 256;
    float v = w[(size_t)o * 512 + c];
    const int pos = (c >> 5) * 32 + (((c >> 3) & 3) ^ swz) * 8 + (c & 7);
    wp[(size_t)o * 512 + pos] = (_Float16)v;
  }
}

// ---------------- pass 1: qkv = conv1x1 via split-fp16 MFMA, global_load_lds staging --------
__global__ __launch_bounds__(256, 4)
void qkv_mfma_kernel(const _Float16* __restrict__ xh, const _Float16* __restrict__ xl,
                     const _Float16* __restrict__ wh, const _Float16* __restrict__ wl,
                     __half* __restrict__ qkvh) {
  const int b     = blockIdx.z;
  const int oBase = blockIdx.y * 128;
  const int nBase = blockIdx.x * 128;
  __shared__ __align__(16) _Float16 S[17408];
  const int tid  = threadIdx.x;
  const int lane = tid & 63;
  const int wid  = tid >> 6;
  const int wo   = (wid >> 1) * 64;
  const int wn   = (wid & 1) * 64;

  f32x4 acc[4][4];
#pragma unroll
  for (int i = 0; i < 4; ++i)
#pragma unroll
    for (int j = 0; j < 4; ++j) acc[i][j] = {0.f, 0.f, 0.f, 0.f};

  const _Float16* sb =
      (wid == 0) ? wh + (size_t)oBase * 256 :
      (wid == 1) ? wl + (size_t)oBase * 256 :
      (wid == 2) ? xh + ((size_t)b * NSP + nBase) * 256 :
                   xl + ((size_t)b * NSP + nBase) * 256;
  const _Float16* lanesrc = sb + (size_t)(lane >> 2) * 256 + (lane & 3) * 8;
  _Float16* plane = S + wid * 4096;

  const int fr = lane & 15;
  const int sl = (lane >> 4) ^ ((fr >> 1) & 3);

  for (int t = 0; t < 8; ++t) {
    const _Float16* ls = lanesrc + t * 32;
#pragma unroll
    for (int i = 0; i < 8; ++i)
      gload16(ls + (size_t)i * 16 * 256, plane + i * 512);
    __syncthreads();

    f16x8 bHf[4], bLf[4];
#pragma unroll
    for (int i = 0; i < 4; ++i) {
      bHf[i] = *(const f16x8*)&S[2 * 4096 + (wn + i * 16 + fr) * 32 + sl * 8];
      bLf[i] = *(const f16x8*)&S[3 * 4096 + (wn + i * 16 + fr) * 32 + sl * 8];
    }
#pragma unroll
    for (int mi = 0; mi < 4; ++mi) {
      f16x8 aHf = *(const f16x8*)&S[0 * 4096 + (wo + mi * 16 + fr) * 32 + sl * 8];
      f16x8 aLf = *(const f16x8*)&S[1 * 4096 + (wo + mi * 16 + fr) * 32 + sl * 8];
#pragma unroll
      for (int ni = 0; ni < 4; ++ni) {
        f32x4 a = acc[mi][ni];
        a = MFMA16(aHf, bHf[ni], a);
        a = MFMA16(aHf, bLf[ni], a);
        a = MFMA16(aLf, bHf[ni], a);
        acc[mi][ni] = a;
      }
    }
    __syncthreads();
  }

  const int orow = (lane >> 4) * 4;
  const int ncol = lane & 15;
#pragma unroll
  for (int mi = 0; mi < 4; ++mi)
#pragma unroll
    for (int ni = 0; ni < 4; ++ni)
#pragma unroll
      for (int r = 0; r < 4; ++r)
        S[(wo + mi * 16 + orow + r) * 136 + wn + ncol + ni * 16] =
            (_Float16)acc[mi][ni][r];
  __syncthreads();
  _Float16* qk = (_Float16*)qkvh;
#pragma unroll
  for (int j = 0; j < 8; ++j) {
    const int c   = j * 256 + tid;
    const int row = c >> 4;
    const int blk = c & 15;
    *(f16x8*)&qk[((size_t)b * CQKV + oBase + row) * NSP + nBase + blk * 8] =
        *(const f16x8*)&S[row * 136 + blk * 8];
  }
}

// ---------------- pass 2: fused depthwise 5x5 + grouped 8x8 pointwise (unchanged) ------------
__global__ __launch_bounds__(256)
void dwpw_kernel(const __half* __restrict__ qkv, const float* __restrict__ wdw,
                 const float* __restrict__ wpw, __half* __restrict__ agg) {
  const int b  = blockIdx.z;
  const int gp = blockIdx.y;
  const int y0 = blockIdx.x * 32;
  const int c0 = gp * 8;
  __shared__ __align__(16) _Float16 tile[8 * 36 * 72 + 8];
  const int tid = threadIdx.x;

  {
    f16x8 zz = {};
    for (int i = tid; i < 2593; i += 256)
      *(f16x8*)&tile[i * 8] = zz;
  }
  __syncthreads();

#pragma unroll
  for (int chs = 0; chs < 8; ++chs) {
    const __half* src = qkv + ((size_t)b * CQKV + c0 + chs) * NSP;
    for (int i = tid; i < 288; i += 256) {
      const int tr = i >> 3, qx = i & 7;
      const int gy = y0 + tr - 2;
      if (gy >= 0 && gy < 64)
        *(f16x8*)&tile[8 + chs * 2592 + tr * 72 + qx * 8] =
            *(const f16x8*)&src[gy * 64 + qx * 8];
    }
  }
  __syncthreads();

  const int tx = tid & 31;
  const int ty = tid >> 5;

  float pwacc[8][4][2];
#pragma unroll
  for (int o = 0; o < 8; ++o)
#pragma unroll
    for (int r = 0; r < 4; ++r) { pwacc[o][r][0] = 0.f; pwacc[o][r][1] = 0.f; }

  typedef _Float16 f16x2 __attribute__((ext_vector_type(2)));
#pragma unroll
  for (int chc = 0; chc < 8; ++chc) {
    const float* wd = wdw + (size_t)(c0 + chc) * 25;
    float dwacc[4][2] = {{0.f, 0.f}, {0.f, 0.f}, {0.f, 0.f}, {0.f, 0.f}};
#pragma unroll
    for (int ir = 0; ir < 8; ++ir) {
      const int base = 8 + chc * 2592 + (4 * ty + ir) * 72 + 2 * tx - 2;
      const f16x2* p = (const f16x2*)&tile[base];
      f16x2 pa = p[0], pb = p[1], pc = p[2];
      float w[6];
      w[0] = (float)pa[0]; w[1] = (float)pa[1];
      w[2] = (float)pb[0]; w[3] = (float)pb[1];
      w[4] = (float)pc[0]; w[5] = (float)pc[1];
#pragma unroll
      for (int o = 0; o < 4; ++o) {
        const int dy = ir - o;
        if (dy >= 0 && dy <= 4) {
#pragma unroll
          for (int dx = 0; dx < 5; ++dx) {
            const float wv = wd[dy * 5 + dx];
            dwacc[o][0] = fmaf(w[dx],     wv, dwacc[o][0]);
            dwacc[o][1] = fmaf(w[dx + 1], wv, dwacc[o][1]);
          }
        }
      }
    }
#pragma unroll
    for (int o = 0; o < 8; ++o) {
      const float pwv = wpw[(size_t)gp * 64 + o * 8 + chc];
#pragma unroll
      for (int r = 0; r < 4; ++r) {
        pwacc[o][r][0] = fmaf(pwv, dwacc[r][0], pwacc[o][r][0]);
        pwacc[o][r][1] = fmaf(pwv, dwacc[r][1], pwacc[o][r][1]);
      }
    }
  }

#pragma unroll
  for (int o = 0; o < 8; ++o) {
#pragma unroll
    for (int r = 0; r < 4; ++r) {
      __half2 hv = __floats2half2_rn(pwacc[o][r][0], pwacc[o][r][1]);
      *(__half2*)&agg[((size_t)b * CQKV + c0 + o) * NSP + (y0 + 4 * ty + r) * 64 + 2 * tx] = hv;
    }
  }
}

// ---------------- pass 3 (materialized): KV reduce + att materialization ----------------
// att layout: [bc][g][n][8] fp16 (bc = chunk-local batch)
__global__ __launch_bounds__(256)
void kvatt_kernel(const __half* __restrict__ qkv, const __half* __restrict__ agg,
                  _Float16* __restrict__ att, int b0) {
  const int g = blockIdx.x;
  const int b = b0 + blockIdx.y;
  const __half* src = (g < 32)
      ? (qkv + ((size_t)b * CQKV + g * 24) * NSP)
      : (agg + ((size_t)b * CQKV + (g - 32) * 24) * NSP);
  const int tid = threadIdx.x;

  float kv[8][9];
#pragma unroll
  for (int d = 0; d < 8; ++d)
#pragma unroll
    for (int e = 0; e < 9; ++e) kv[d][e] = 0.f;

  for (int i = 0; i < 4; ++i) {
    const int n0 = i * 1024 + tid * 4;
    Half4 kh[8], vh[8];
#pragma unroll
    for (int d = 0; d < 8; ++d) kh[d] = *(const Half4*)&src[(size_t)(8 + d) * NSP + n0];
#pragma unroll
    for (int e = 0; e < 8; ++e) vh[e] = *(const Half4*)&src[(size_t)(16 + e) * NSP + n0];
#pragma unroll
    for (int j = 0; j < 4; ++j) {
      float kk[8], vv[8];
#pragma unroll
      for (int d = 0; d < 8; ++d) kk[d] = fmaxf(__half2float(kh[d].v[j]), 0.f);
#pragma unroll
      for (int e = 0; e < 8; ++e) vv[e] = __half2float(vh[e].v[j]);
#pragma unroll
      for (int d = 0; d < 8; ++d) {
#pragma unroll
        for (int e = 0; e < 8; ++e) kv[d][e] = fmaf(kk[d], vv[e], kv[d][e]);
        kv[d][8] += kk[d];
      }
    }
  }

  __shared__ float red[4][72];
  __shared__ float kvs[72];
  const int lane = tid & 63;
  const int wv   = tid >> 6;
#pragma unroll
  for (int d = 0; d < 8; ++d)
#pragma unroll
    for (int e = 0; e < 9; ++e) {
      float v = kv[d][e];
      v += __shfl_xor(v, 32);
      v += __shfl_xor(v, 16);
      v += __shfl_xor(v, 8);
      v += __shfl_xor(v, 4);
      v += __shfl_xor(v, 2);
      v += __shfl_xor(v, 1);
      kv[d][e] = v;
    }
  if (lane == 0) {
#pragma unroll
    for (int d = 0; d < 8; ++d)
#pragma unroll
      for (int e = 0; e < 9; ++e) red[wv][d * 9 + e] = kv[d][e];
  }
  __syncthreads();
  if (tid < 72) kvs[tid] = red[0][tid] + red[1][tid] + red[2][tid] + red[3][tid];
  __syncthreads();

  float kvr[8][9];
#pragma unroll
  for (int d = 0; d < 8; ++d)
#pragma unroll
    for (int e = 0; e < 9; ++e) kvr[d][e] = kvs[d * 9 + e];

  // phase 2: att[n][e] = relu(q)·kv / den
  _Float16* dst = att + ((size_t)blockIdx.y * 64 + g) * NSP * 8;
  for (int i = 0; i < 4; ++i) {
    const int n0 = i * 1024 + tid * 4;
    Half4 qh[8];
#pragma unroll
    for (int d = 0; d < 8; ++d) qh[d] = *(const Half4*)&src[(size_t)d * NSP + n0];
#pragma unroll
    for (int j = 0; j < 4; ++j) {
      float q[8];
#pragma unroll
      for (int d = 0; d < 8; ++d) q[d] = fmaxf(__half2float(qh[d].v[j]), 0.f);
      float num[9];
#pragma unroll
      for (int e = 0; e < 9; ++e) {
        float s = 0.f;
#pragma unroll
        for (int d = 0; d < 8; ++d) s = fmaf(q[d], kvr[d][e], s);
        num[e] = s;
      }
      const float r = 1.f / (num[8] + EPS);
      f16x8 o8;
#pragma unroll
      for (int e = 0; e < 8; ++e) o8[e] = (_Float16)(num[e] * r);
      *(f16x8*)&dst[(size_t)(n0 + j) * 8] = o8;
    }
  }
}

// ---------------- pass 4 (materialized): proj GEMM, qkv-style, + BN ----------------
__global__ __launch_bounds__(256, 4)
void proj2_kernel(const _Float16* __restrict__ att, const _Float16* __restrict__ wp,
                  float* __restrict__ out,
                  const float* __restrict__ gamma, const float* __restrict__ beta,
                  const float* __restrict__ mean, const float* __restrict__ var, int b0) {
  const int bz    = blockIdx.z;         // chunk-local batch
  const int b     = b0 + bz;
  const int oBase = blockIdx.y * 128;
  const int nBase = blockIdx.x * 128;
  __shared__ __align__(16) _Float16 S[2 * 4096];
  const int tid  = threadIdx.x;
  const int lane = tid & 63;
  const int wid  = tid >> 6;
  const int wo   = (wid >> 1) * 64;
  const int wn   = (wid & 1) * 64;

  f32x4 acc[4][4];
#pragma unroll
  for (int i = 0; i < 4; ++i)
#pragma unroll
    for (int j = 0; j < 4; ++j) acc[i][j] = {0.f, 0.f, 0.f, 0.f};

  const _Float16* wpb  = wp + (size_t)oBase * 512;
  const _Float16* attb = att + (size_t)bz * 64 * NSP * 8;

  const int fr = lane & 15;
  const int sl = (lane >> 4) ^ ((fr >> 1) & 3);

  for (int t = 0; t < 16; ++t) {
#pragma unroll
    for (int i = 0; i < 2; ++i) {
      const int c  = tid + i * 256;       // chunk 0..511
      const int r  = c >> 2;              // row / n-local
      const int cb = c & 3;               // 16B slot in 32-half group
      // A: pre-swizzled source, linear copy
      gload16(wpb + (size_t)r * 512 + t * 32 + cb * 8, &S[c * 8]);
      // B: inverse-swizzle at source: slot cb holds group-block cb ^ key(n)
      const int g = t * 4 + (cb ^ ((c >> 3) & 3));
      gload16(attb + ((size_t)g * NSP + nBase + r) * 8, &S[4096 + c * 8]);
    }
    __syncthreads();

    f16x8 bf[4];
#pragma unroll
    for (int i = 0; i < 4; ++i)
      bf[i] = *(const f16x8*)&S[4096 + (wn + i * 16 + fr) * 32 + sl * 8];
#pragma unroll
    for (int mi = 0; mi < 4; ++mi) {
      f16x8 af = *(const f16x8*)&S[(wo + mi * 16 + fr) * 32 + sl * 8];
#pragma unroll
      for (int ni = 0; ni < 4; ++ni)
        acc[mi][ni] = MFMA16(af, bf[ni], acc[mi][ni]);
    }
    __syncthreads();
  }

  const int orow = (lane >> 4) * 4;
  const int ncol = lane & 15;
#pragma unroll
  for (int mi = 0; mi < 4; ++mi) {
#pragma unroll
    for (int r = 0; r < 4; ++r) {
      const int o = oBase + wo + mi * 16 + orow + r;
      const float inv  = gamma[o] / sqrtf(var[o] + 1e-5f);
      const float bias = beta[o] - mean[o] * inv;
      float* dst = out + ((size_t)b * 256 + o) * NSP + nBase + wn + ncol;
#pragma unroll
      for (int ni = 0; ni < 4; ++ni)
        dst[ni * 16] = acc[mi][ni][r] * inv + bias;
    }
  }
}

// ---------------- fallback pass 3: KV matrices to global ----------------
__global__ __launch_bounds__(256)
void kv_kernel(const __half* __restrict__ qkv, const __half* __restrict__ agg,
               float* __restrict__ kvmat) {
  const int g = blockIdx.x;
  const int b = blockIdx.y;
  const __half* src = (g < 32)
      ? (qkv + ((size_t)b * CQKV + g * 24) * NSP)
      : (agg + ((size_t)b * CQKV + (g - 32) * 24) * NSP);
  const int tid = threadIdx.x;

  float kv[8][9];
#pragma unroll
  for (int d = 0; d < 8; ++d)
#pragma unroll
    for (int e = 0; e < 9; ++e) kv[d][e] = 0.f;

  for (int i = 0; i < 4; ++i) {
    const int n0 = i * 1024 + tid * 4;
    Half4 kh[8], vh[8];
#pragma unroll
    for (int d = 0; d < 8; ++d) kh[d] = *(const Half4*)&src[(size_t)(8 + d) * NSP + n0];
#pragma unroll
    for (int e = 0; e < 8; ++e) vh[e] = *(const Half4*)&src[(size_t)(16 + e) * NSP + n0];
#pragma unroll
    for (int j = 0; j < 4; ++j) {
      float kk[8], vv[8];
#pragma unroll
      for (int d = 0; d < 8; ++d) kk[d] = fmaxf(__half2float(kh[d].v[j]), 0.f);
#pragma unroll
      for (int e = 0; e < 8; ++e) vv[e] = __half2float(vh[e].v[j]);
#pragma unroll
      for (int d = 0; d < 8; ++d) {
#pragma unroll
        for (int e = 0; e < 8; ++e) kv[d][e] = fmaf(kk[d], vv[e], kv[d][e]);
        kv[d][8] += kk[d];
      }
    }
  }

  __shared__ float red[4][72];
  const int lane = tid & 63;
  const int wv   = tid >> 6;
#pragma unroll
  for (int d = 0; d < 8; ++d)
#pragma unroll
    for (int e = 0; e < 9; ++e) {
      float v = kv[d][e];
      v += __shfl_xor(v, 32);
      v += __shfl_xor(v, 16);
      v += __shfl_xor(v, 8);
      v += __shfl_xor(v, 4);
      v += __shfl_xor(v, 2);
      v += __shfl_xor(v, 1);
      kv[d][e] = v;
    }
  if (lane == 0) {
#pragma unroll
    for (int d = 0; d < 8; ++d)
#pragma unroll
      for (int e = 0; e < 9; ++e) red[wv][d * 9 + e] = kv[d][e];
  }
  __syncthreads();
  if (tid < 72) {
    kvmat[((size_t)b * 64 + g) * 72 + tid] =
        red[0][tid] + red[1][tid] + red[2][tid] + red[3][tid];
  }
}

// ---------------- fallback pass 4: fused proj GEMM ----------------
__global__ __launch_bounds__(256)
void proj_mfma_kernel(const __half* __restrict__ qkvh, const __half* __restrict__ aggh,
                      const float* __restrict__ kvmat, const float* __restrict__ Wp,
                      float* __restrict__ out,
                      const float* __restrict__ gamma, const float* __restrict__ beta,
                      const float* __restrict__ mean, const float* __restrict__ var) {
  const int b     = blockIdx.z;
  const int oBase = blockIdx.y * 128;
  const int nBase = blockIdx.x * 128;
  __shared__ _Float16 As[2][128 * 32];
  __shared__ _Float16 Bs[2][128 * 32];
  __shared__ float KvS[64 * 72];
  const int tid  = threadIdx.x;
  const int lane = tid & 63;
  const int wid  = tid >> 6;
  const int wo   = (wid >> 1) * 64;
  const int wn   = (wid & 1) * 64;

  for (int i = tid; i < 64 * 72; i += 256) KvS[i] = kvmat[(size_t)b * 4608 + i];

  f32x4 acc[4][4];
#pragma unroll
  for (int i = 0; i < 4; ++i)
#pragma unroll
    for (int j = 0; j < 4; ++j) acc[i][j] = {0.f, 0.f, 0.f, 0.f};

  const int r0  = tid >> 2;
  const int cb0 = tid & 3;
  const int s0  = cb0 ^ ((r0 >> 1) & 3);
  const int np0 = tid & 127;
  const int glA = tid >> 7;
  const int glB = 2 + (tid >> 7);
  const int sbA = glA ^ ((np0 >> 1) & 3);
  const int sbB = glB ^ ((np0 >> 1) & 3);

  const float* wb = Wp + (size_t)oBase * 512;

  f16x8 ra[2];
  _Float16 qh[2][8];

  auto LOADS = [&](int t) {
    const int k0 = t * 32 + cb0 * 8;
    const float* p0 = wb + (size_t)r0 * 512 + k0;
    ra[0] = cvt8(*(const float4*)p0, *(const float4*)(p0 + 4));
    const float* p1 = wb + (size_t)(r0 + 64) * 512 + k0;
    ra[1] = cvt8(*(const float4*)p1, *(const float4*)(p1 + 4));
#pragma unroll
    for (int pi = 0; pi < 2; ++pi) {
      const int gg = t * 4 + (pi == 0 ? glA : glB);
      const __half* src = (gg < 32)
          ? (qkvh + ((size_t)b * CQKV + gg * 24) * NSP)
          : (aggh + ((size_t)b * CQKV + (gg - 32) * 24) * NSP);
      const __half* sp = src + nBase + np0;
#pragma unroll
      for (int d = 0; d < 8; ++d) qh[pi][d] = *(const _Float16*)(sp + (size_t)d * NSP);
    }
  };

  auto BUILD = [&](int t, int buf) {
    *(f16x8*)&As[buf][r0 * 32 + s0 * 8]        = ra[0];
    *(f16x8*)&As[buf][(r0 + 64) * 32 + s0 * 8] = ra[1];
#pragma unroll
    for (int pi = 0; pi < 2; ++pi) {
      const int gg = t * 4 + (pi == 0 ? glA : glB);
      const float* kv = &KvS[gg * 72];
      float q[8];
#pragma unroll
      for (int d = 0; d < 8; ++d) q[d] = fmaxf((float)qh[pi][d], 0.f);
      float den = 0.f;
#pragma unroll
      for (int d = 0; d < 8; ++d) den = fmaf(q[d], kv[d * 9 + 8], den);
      const float rden = 1.f / (den + EPS);
      f16x8 hv;
#pragma unroll
      for (int e = 0; e < 8; ++e) {
        float num = 0.f;
#pragma unroll
        for (int d = 0; d < 8; ++d) num = fmaf(q[d], kv[d * 9 + e], num);
        hv[e] = (_Float16)(num * rden);
      }
      *(f16x8*)&Bs[buf][np0 * 32 + (pi == 0 ? sbA : sbB) * 8] = hv;
    }
    __syncthreads();
  };

  const int fr = lane & 15;
  const int sl = (lane >> 4) ^ ((fr >> 1) & 3);

  LOADS(0);
  __syncthreads();
  BUILD(0, 0);
  int cur = 0;
  for (int t = 0; t < 16; ++t) {
    if (t < 15) LOADS(t + 1);
    f16x8 af[4], bf[4];
#pragma unroll
    for (int i = 0; i < 4; ++i) {
      af[i] = *(const f16x8*)&As[cur][(wo + i * 16 + fr) * 32 + sl * 8];
      bf[i] = *(const f16x8*)&Bs[cur][(wn + i * 16 + fr) * 32 + sl * 8];
    }
#pragma unroll
    for (int mi = 0; mi < 4; ++mi)
#pragma unroll
      for (int ni = 0; ni < 4; ++ni)
        acc[mi][ni] = MFMA16(af[mi], bf[ni], acc[mi][ni]);
    if (t < 15) BUILD(t + 1, cur ^ 1);
    cur ^= 1;
  }

  const int orow = (lane >> 4) * 4;
  const int ncol = lane & 15;
#pragma unroll
  for (int mi = 0; mi < 4; ++mi) {
#pragma unroll
    for (int r = 0; r < 4; ++r) {
      const int o = oBase + wo + mi * 16 + orow + r;
      const float inv  = gamma[o] / sqrtf(var[o] + 1e-5f);
      const float bias = beta[o] - mean[o] * inv;
      float* dst = out + ((size_t)b * 256 + o) * NSP + nBase + wn + ncol;
#pragma unroll
      for (int ni = 0; ni < 4; ++ni)
        dst[ni * 16] = acc[mi][ni][r] * inv + bias;
    }
  }
}

}  // namespace

extern "C" void kernel_launch(void* const* d_in, const int* in_sizes, int n_in,
                              void* d_out, int out_size, void* d_ws, size_t ws_size,
                              hipStream_t stream) {
  const float* x      = (const float*)d_in[0];
  const float* w_qkv  = (const float*)d_in[1];
  const float* w_dw   = (const float*)d_in[2];
  const float* w_pw   = (const float*)d_in[3];
  const float* w_proj = (const float*)d_in[4];
  const float* gamma  = (const float*)d_in[5];
  const float* beta   = (const float*)d_in[6];
  const float* mean   = (const float*)d_in[7];
  const float* var    = (const float*)d_in[8];
  float* out = (float*)d_out;

  const size_t nQ = (size_t)BATCH * CQKV * NSP;   // 50,331,648 halfs (96 MiB)
  __half* qkvh = (__half*)d_ws;
  __half* aggh = qkvh + nQ;
  float*  kvm  = (float*)(aggh + nQ);             // fallback only

  // x/w split planes alias the agg region (dead until dwpw writes it)
  const size_t nX = (size_t)BATCH * NSP * 256;
  _Float16* xtH = (_Float16*)aggh;
  _Float16* xtL = xtH + nX;
  _Float16* wH  = xtL + nX;
  _Float16* wL  = wH + (size_t)CQKV * 256;

  // materialized-att region (past the proven-safe base)
  const size_t baseBytes = 2 * nQ * 2 + (size_t)BATCH * 64 * 72 * 4;  // 201,621,504
  _Float16* wp16 = (_Float16*)((char*)d_ws + baseBytes);
  _Float16* attm = wp16 + (size_t)256 * 512;
  const size_t wpBytes = (size_t)256 * 512 * 2;
  int BC = 0;
  for (int c = 16; c >= 1; c >>= 1)
    if (baseBytes + wpBytes + (size_t)c * 64 * NSP * 8 * 2 <= ws_size) { BC = c; break; }

  // 0) prep
  xprep_kernel<<<dim3(64, 4, BATCH), 256, 0, stream>>>(x, xtH, xtL);
  wprep_kernel<<<dim3(CQKV), 256, 0, stream>>>(w_qkv, wH, wL);
  if (BC) wprep2_kernel<<<dim3(256), 256, 0, stream>>>(w_proj, wp16);

  // 1) qkv GEMM
  qkv_mfma_kernel<<<dim3(NSP / 128, CQKV / 128, BATCH), 256, 0, stream>>>(
      xtH, xtL, wH, wL, qkvh);

  // 2) dw + grouped pw
  dwpw_kernel<<<dim3(2, 96, BATCH), 256, 0, stream>>>(qkvh, w_dw, w_pw, aggh);

  if (BC) {
    // 3/4) materialized attention + clean proj GEMM, chunked over batch
    for (int b0 = 0; b0 < BATCH; b0 += BC) {
      kvatt_kernel<<<dim3(64, BC), 256, 0, stream>>>(qkvh, aggh, attm, b0);
      proj2_kernel<<<dim3(NSP / 128, 2, BC), 256, 0, stream>>>(
          attm, wp16, out, gamma, beta, mean, var, b0);
    }
  } else {
    // fallback: fused path (known-good)
    kv_kernel<<<dim3(64, BATCH), 256, 0, stream>>>(qkvh, aggh, kvm);
    proj_mfma_kernel<<<dim3(NSP / 128, 2, BATCH), 256, 0, stream>>>(
        qkvh, aggh, kvm, w_proj, out, gamma, beta, mean, var);
  }
}